// Round 9
// baseline (365.670 us; speedup 1.0000x reference)
//
#include <hip/hip_runtime.h>

#define GRAPHS 128
#define CHUNKC 8000

typedef _Float16 f16x8 __attribute__((ext_vector_type(8)));
typedef _Float16 f16x4 __attribute__((ext_vector_type(4)));
typedef _Float16 f16x2 __attribute__((ext_vector_type(2)));
typedef float f32x4 __attribute__((ext_vector_type(4)));

// ============ CSR build: bucket counting sort, XCD-local writes ============
__global__ void k_hist(const int* __restrict__ dst, int* __restrict__ histG,
                       int e, int NB, int NW) {
  __shared__ int h[256];
  int t = threadIdx.x, w = blockIdx.x;
  h[t] = 0; __syncthreads();
  int lo = w * CHUNKC, hi = min(lo + CHUNKC, e);
  for (int i = lo + t; i < hi; i += 256) atomicAdd(&h[dst[i] >> 9], 1);
  __syncthreads();
  if (t < NB) histG[t * NW + w] = h[t];
}

// ---- 3-phase parallel exclusive scan of N ints ----
__global__ void k_scanA(const int* __restrict__ in, int* __restrict__ out,
                        int* __restrict__ bsum, int N) {
  __shared__ int s[256];
  int t = threadIdx.x, b = blockIdx.x;
  int base = b * 1024 + t * 4;
  int v[4]; int tot = 0;
#pragma unroll
  for (int j = 0; j < 4; ++j) { int i = base + j; v[j] = (i < N) ? in[i] : 0; tot += v[j]; }
  s[t] = tot; __syncthreads();
  for (int o = 1; o < 256; o <<= 1) {
    int x = (t >= o) ? s[t - o] : 0;
    __syncthreads(); s[t] += x; __syncthreads();
  }
  int run = s[t] - tot;
#pragma unroll
  for (int j = 0; j < 4; ++j) { int i = base + j; if (i < N) out[i] = run; run += v[j]; }
  if (t == 255) bsum[b] = s[255];
}

__global__ void k_scanB(int* bsum, int nb) {  // 1 block, nb <= 256
  __shared__ int s[256];
  int t = threadIdx.x;
  int v = (t < nb) ? bsum[t] : 0;
  s[t] = v; __syncthreads();
  for (int o = 1; o < 256; o <<= 1) {
    int x = (t >= o) ? s[t - o] : 0;
    __syncthreads(); s[t] += x; __syncthreads();
  }
  if (t < nb) bsum[t] = s[t] - v;
}

__global__ void k_scanC(int* __restrict__ out, const int* __restrict__ bsum, int N) {
  int i = blockIdx.x * 256 + threadIdx.x;
  if (i < N) out[i] += bsum[i >> 10];
}

__global__ void k_part(const int* __restrict__ src, const int* __restrict__ dst,
                       const int* __restrict__ histG, const int* __restrict__ off,
                       int* __restrict__ part, int e, int NB, int NW) {
  __shared__ int hist[256], lbA[256], lbB[256], stmp[256];
  __shared__ int els[CHUNKC];
  int t = threadIdx.x, w = blockIdx.x;
  int hv = (t < NB) ? histG[t * NW + w] : 0;
  hist[t] = hv; stmp[t] = hv; __syncthreads();
  for (int o = 1; o < 256; o <<= 1) {
    int x = (t >= o) ? stmp[t - o] : 0;
    __syncthreads(); stmp[t] += x; __syncthreads();
  }
  lbA[t] = stmp[t] - hv; lbB[t] = stmp[t] - hv;
  __syncthreads();
  int lo = w * CHUNKC, hi = min(lo + CHUNKC, e);
  for (int i = lo + t; i < hi; i += 256) {
    int d = dst[i];
    int p = atomicAdd(&lbB[d >> 9], 1);
    els[p] = src[i] | ((d & 511) << 17);   // src < 2^17, dstlow < 2^9
  }
  __syncthreads();
  int ln = t & 63, wv = t >> 6;
  for (int b = wv; b < NB; b += 4) {
    int c = hist[b], lb = lbA[b];
    long g = off[b * NW + w];
    for (int j = ln; j < c; j += 64) part[g + j] = els[lb + j];
  }
}

__global__ void k_csrb(const int* __restrict__ part, const int* __restrict__ off,
                       int* __restrict__ ptr, int* __restrict__ csr,
                       int e, int NB, int NW, int n) {
  __shared__ int nh[512], ncur[512], stmp[256];
  int t = threadIdx.x, b = blockIdx.x;
  int s0 = off[b * NW];
  int e0 = (b + 1 < NB) ? off[(b + 1) * NW] : e;
  nh[t] = 0; nh[t + 256] = 0; __syncthreads();
  for (int i = s0 + t; i < e0; i += 256) atomicAdd(&nh[((unsigned)part[i]) >> 17], 1);
  __syncthreads();
  int v0 = nh[2 * t], v1 = nh[2 * t + 1];
  int ps = v0 + v1;
  stmp[t] = ps; __syncthreads();
  for (int o = 1; o < 256; o <<= 1) {
    int x = (t >= o) ? stmp[t - o] : 0;
    __syncthreads(); stmp[t] += x; __syncthreads();
  }
  int base = stmp[t] - ps;
  __syncthreads();
  nh[2 * t] = base;   nh[2 * t + 1] = base + v0;
  ncur[2 * t] = base; ncur[2 * t + 1] = base + v0;
  __syncthreads();
#pragma unroll
  for (int q = 0; q < 2; ++q) {
    int vv = t + q * 256;
    int node = (b << 9) + vv;
    if (node <= n) ptr[node] = s0 + nh[vv];   // covers sentinel ptr[n]=e
  }
  for (int i = s0 + t; i < e0; i += 256) {
    int u = part[i];
    int p = atomicAdd(&ncur[((unsigned)u) >> 17], 1);
    csr[s0 + p] = u & 0x1FFFF;
  }
}

// ---------------- fp32 -> f16 conversion (x only) ----------------
__global__ void k_cvt(const float* __restrict__ in, _Float16* __restrict__ out, int total4) {
  int i = blockIdx.x * 256 + threadIdx.x;
  if (i >= total4) return;
  float4 v = ((const float4*)in)[i];
  f16x4 h = { (_Float16)v.x, (_Float16)v.y, (_Float16)v.z, (_Float16)v.w };
  ((f16x4*)out)[i] = h;
}

// ------------- aggregation: out[i] = in[i] + sum_N in[j], f16, f32 accum -------------
__global__ void k_agg_h(const _Float16* __restrict__ in, _Float16* __restrict__ out,
                        const int* __restrict__ ptr, const int* __restrict__ csr, int n) {
  int gid = blockIdx.x * 256 + threadIdx.x;
  int node = gid >> 6, lane = gid & 63;
  if (node >= n) return;
  const f16x8* inp = (const f16x8*)in;
  int cb = lane & 15, rg = lane >> 4;
  f16x8 self = inp[(size_t)node * 16 + cb];
  float acc[8];
#pragma unroll
  for (int c = 0; c < 8; ++c) acc[c] = (rg == 0) ? (float)self[c] : 0.f;
  int s = ptr[node], deg = ptr[node + 1] - s;
  for (int seg = 0; seg < deg; seg += 64) {
    int my = (seg + lane < deg) ? csr[s + seg + lane] : n;
    int segn = min(deg - seg, 64);
    for (int b2 = 0; b2 < segn; b2 += 32) {
      int jj[8]; f16x8 w[8];
#pragma unroll
      for (int u = 0; u < 8; ++u) jj[u] = __shfl(my, b2 + u * 4 + rg);
#pragma unroll
      for (int u = 0; u < 8; ++u) w[u] = inp[(size_t)jj[u] * 16 + cb];
#pragma unroll
      for (int u = 0; u < 8; ++u)
#pragma unroll
        for (int c = 0; c < 8; ++c) acc[c] += (float)w[u][c];
    }
  }
#pragma unroll
  for (int c = 0; c < 8; ++c) {
    acc[c] += __shfl_xor(acc[c], 16);
    acc[c] += __shfl_xor(acc[c], 32);
  }
  if (rg == 0) {
    f16x8 r;
#pragma unroll
    for (int c = 0; c < 8; ++c) r[c] = (_Float16)acc[c];
    ((f16x8*)out)[(size_t)node * 16 + cb] = r;
  }
}

// -------- weight prep (all 4 mats): W[k][c] fp32 -> Wt[c][k] f16 --------
__global__ void k_wprep_all(const float* __restrict__ W11, const float* __restrict__ W12,
                            const float* __restrict__ W21, const float* __restrict__ W22,
                            _Float16* __restrict__ w11t, _Float16* __restrict__ w12t,
                            _Float16* __restrict__ w21t, _Float16* __restrict__ w22t) {
  int b = blockIdx.x, k = threadIdx.x;
  const float* W; _Float16* Wt; int c, C;
  if (b < 128)      { W = W11; Wt = w11t; c = b;       C = 128; }
  else if (b < 256) { W = W12; Wt = w12t; c = b - 128; C = 128; }
  else if (b < 384) { W = W21; Wt = w21t; c = b - 256; C = 128; }
  else              { W = W22; Wt = w22t; c = b - 384; C = 256; }
  Wt[c * 128 + k] = (_Float16)W[k * C + c];
}

// ------- fused MLP: out = relu(relu(in@WA+bA)@WB+bB), 128->128->128 -------
// Barrier-free: A-frags from GLOBAL (own rows), B-frags from GLOBAL (L1/L2-hot,
// identical across waves), only h goes through LDS and each wave touches ONLY
// its own 32 rows. 128-row tile, 256 thr, LDS 34.8 KB -> 4 blocks/CU.
__launch_bounds__(256)
__global__ void k_mlp128(const _Float16* __restrict__ in, const _Float16* __restrict__ WtA,
                         const float* __restrict__ bA, const _Float16* __restrict__ WtB,
                         const float* __restrict__ bB, _Float16* __restrict__ out, int n) {
  __shared__ _Float16 hs[128 * 136];
  int t = threadIdx.x;
  int r0 = blockIdx.x * 128;
  int lane = t & 63, w = t >> 6;
  int l16 = lane & 15, rg = lane >> 4;
  int rw = w * 32;
  const f16x8* inp = (const f16x8*)in;
  const f16x8* wa = (const f16x8*)WtA;
  const f16x8* wb = (const f16x8*)WtB;
  int ra0 = r0 + rw + l16;       if (ra0 > n) ra0 = n;   // row n = finite pad row
  int ra1 = r0 + rw + 16 + l16;  if (ra1 > n) ra1 = n;
  f32x4 acc[2][8];
#pragma unroll
  for (int fr = 0; fr < 2; ++fr)
#pragma unroll
    for (int fc = 0; fc < 8; ++fc) acc[fr][fc] = (f32x4){0.f, 0.f, 0.f, 0.f};
  // ---- layer A: a from global, b from global
#pragma unroll
  for (int kk = 0; kk < 4; ++kk) {
    int ck = kk * 4 + rg;
    f16x8 a0 = inp[(size_t)ra0 * 16 + ck];
    f16x8 a1 = inp[(size_t)ra1 * 16 + ck];
#pragma unroll
    for (int fc = 0; fc < 8; ++fc) {
      f16x8 b = wa[(fc * 16 + l16) * 16 + ck];
      acc[0][fc] = __builtin_amdgcn_mfma_f32_16x16x32_f16(a0, b, acc[0][fc], 0, 0, 0);
      acc[1][fc] = __builtin_amdgcn_mfma_f32_16x16x32_f16(a1, b, acc[1][fc], 0, 0, 0);
    }
  }
  // ---- h -> LDS (own rows only; wave-private region, no barrier)
  int rloc = rw + rg * 4;
#pragma unroll
  for (int fc = 0; fc < 8; ++fc) {
    int col = fc * 16 + l16;
    float bv = bA[col];
#pragma unroll
    for (int fr = 0; fr < 2; ++fr)
#pragma unroll
      for (int j = 0; j < 4; ++j)
        hs[(rloc + fr * 16 + j) * 136 + col] = (_Float16)fmaxf(acc[fr][fc][j] + bv, 0.f);
  }
  // ---- layer B: a from LDS h (own rows), b from global
#pragma unroll
  for (int fr = 0; fr < 2; ++fr)
#pragma unroll
    for (int fc = 0; fc < 8; ++fc) acc[fr][fc] = (f32x4){0.f, 0.f, 0.f, 0.f};
#pragma unroll
  for (int kk = 0; kk < 4; ++kk) {
    int klo = kk * 32 + rg * 8;
    f16x8 a0 = *(const f16x8*)&hs[(rw + l16) * 136 + klo];
    f16x8 a1 = *(const f16x8*)&hs[(rw + 16 + l16) * 136 + klo];
#pragma unroll
    for (int fc = 0; fc < 8; ++fc) {
      f16x8 b = wb[(fc * 16 + l16) * 16 + kk * 4 + rg];
      acc[0][fc] = __builtin_amdgcn_mfma_f32_16x16x32_f16(a0, b, acc[0][fc], 0, 0, 0);
      acc[1][fc] = __builtin_amdgcn_mfma_f32_16x16x32_f16(a1, b, acc[1][fc], 0, 0, 0);
    }
  }
#pragma unroll
  for (int fc = 0; fc < 8; ++fc) {
    int col = fc * 16 + l16;
    float bv = bB[col];
#pragma unroll
    for (int fr = 0; fr < 2; ++fr)
#pragma unroll
      for (int j = 0; j < 4; ++j) {
        int row = r0 + rloc + fr * 16 + j;
        if (row < n) out[(size_t)row * 128 + col] = (_Float16)fmaxf(acc[fr][fc][j] + bv, 0.f);
      }
  }
}

// ------- fused MLP + pool: relu(relu(in@W21+b21)@W22+b22) summed per graph -------
// Same barrier-free structure; 2 barriers only for pool_l init/flush.
__launch_bounds__(256)
__global__ void k_mlp_pool(const _Float16* __restrict__ in, const _Float16* __restrict__ WtA,
                           const float* __restrict__ bA, const _Float16* __restrict__ WtB,
                           const float* __restrict__ bB, const int* __restrict__ batch,
                           float* __restrict__ pool, int n) {
  __shared__ _Float16 hs[128 * 136];
  __shared__ float pool_l[8 * 256];
  int t = threadIdx.x;
  int r0 = blockIdx.x * 128;
#pragma unroll
  for (int j = 0; j < 8; ++j) pool_l[j * 256 + t] = 0.f;
  __syncthreads();
  int lane = t & 63, w = t >> 6;
  int l16 = lane & 15, rg = lane >> 4;
  int rw = w * 32;
  const f16x8* inp = (const f16x8*)in;
  const f16x8* wa = (const f16x8*)WtA;
  const f16x8* wb = (const f16x8*)WtB;
  int ra0 = r0 + rw + l16;       if (ra0 > n) ra0 = n;
  int ra1 = r0 + rw + 16 + l16;  if (ra1 > n) ra1 = n;
  int rloc = rw + rg * 4;
  int g0 = batch[r0];
  int g4[2][4];
#pragma unroll
  for (int fr = 0; fr < 2; ++fr)
#pragma unroll
    for (int j = 0; j < 4; ++j) {
      int row = r0 + rloc + fr * 16 + j;
      g4[fr][j] = (row < n) ? batch[row] : -1;
    }
  f32x4 acc[2][8];
  // ---- layer A (W21)
#pragma unroll
  for (int fr = 0; fr < 2; ++fr)
#pragma unroll
    for (int fc = 0; fc < 8; ++fc) acc[fr][fc] = (f32x4){0.f, 0.f, 0.f, 0.f};
#pragma unroll
  for (int kk = 0; kk < 4; ++kk) {
    int ck = kk * 4 + rg;
    f16x8 a0 = inp[(size_t)ra0 * 16 + ck];
    f16x8 a1 = inp[(size_t)ra1 * 16 + ck];
#pragma unroll
    for (int fc = 0; fc < 8; ++fc) {
      f16x8 b = wa[(fc * 16 + l16) * 16 + ck];
      acc[0][fc] = __builtin_amdgcn_mfma_f32_16x16x32_f16(a0, b, acc[0][fc], 0, 0, 0);
      acc[1][fc] = __builtin_amdgcn_mfma_f32_16x16x32_f16(a1, b, acc[1][fc], 0, 0, 0);
    }
  }
#pragma unroll
  for (int fc = 0; fc < 8; ++fc) {
    int col = fc * 16 + l16;
    float bv = bA[col];
#pragma unroll
    for (int fr = 0; fr < 2; ++fr)
#pragma unroll
      for (int j = 0; j < 4; ++j)
        hs[(rloc + fr * 16 + j) * 136 + col] = (_Float16)fmaxf(acc[fr][fc][j] + bv, 0.f);
  }
  // ---- layer B (W22), two 128-col halves, b-frags straight from global
  for (int h = 0; h < 2; ++h) {
#pragma unroll
    for (int fr = 0; fr < 2; ++fr)
#pragma unroll
      for (int fc = 0; fc < 8; ++fc) acc[fr][fc] = (f32x4){0.f, 0.f, 0.f, 0.f};
#pragma unroll
    for (int kk = 0; kk < 4; ++kk) {
      int klo = kk * 32 + rg * 8;
      f16x8 a0 = *(const f16x8*)&hs[(rw + l16) * 136 + klo];
      f16x8 a1 = *(const f16x8*)&hs[(rw + 16 + l16) * 136 + klo];
#pragma unroll
      for (int fc = 0; fc < 8; ++fc) {
        f16x8 b = wb[(h * 128 + fc * 16 + l16) * 16 + kk * 4 + rg];
        acc[0][fc] = __builtin_amdgcn_mfma_f32_16x16x32_f16(a0, b, acc[0][fc], 0, 0, 0);
        acc[1][fc] = __builtin_amdgcn_mfma_f32_16x16x32_f16(a1, b, acc[1][fc], 0, 0, 0);
      }
    }
#pragma unroll
    for (int fc = 0; fc < 8; ++fc) {
      int col = h * 128 + fc * 16 + l16;
      float bv = bB[col];
#pragma unroll
      for (int fr = 0; fr < 2; ++fr) {
        f32x4 a = acc[fr][fc];
        float run = fmaxf(a[0] + bv, 0.f);
#pragma unroll
        for (int j = 1; j < 4; ++j) {
          float v = fmaxf(a[j] + bv, 0.f);
          if (g4[fr][j] == g4[fr][j - 1]) run += v;
          else {
            int g = g4[fr][j - 1];
            if (g >= 0) {
              int d = g - g0;
              if (d >= 0 && d < 8) atomicAdd(&pool_l[d * 256 + col], run);
              else atomicAdd(&pool[g * 256 + col], run);
            }
            run = v;
          }
        }
        int g = g4[fr][3];
        if (g >= 0) {
          int d = g - g0;
          if (d >= 0 && d < 8) atomicAdd(&pool_l[d * 256 + col], run);
          else atomicAdd(&pool[g * 256 + col], run);
        }
      }
    }
  }
  __syncthreads();
#pragma unroll
  for (int j = 0; j < 8; ++j) {
    int idx = j * 256 + t;
    int g = g0 + (idx >> 8), col = idx & 255;
    float v = pool_l[idx];
    if (g < GRAPHS && v != 0.f) atomicAdd(&pool[g * 256 + col], v);
  }
}

// ---------------- graph boundaries + LayerNorm finalize ----------------
__global__ void k_starts(const int* __restrict__ batch, int* __restrict__ starts, int n) {
  int g = threadIdx.x;
  if (g > GRAPHS) return;
  int lo = 0, hi = n;
  while (lo < hi) { int mid = (lo + hi) >> 1; if (batch[mid] < g) lo = mid + 1; else hi = mid; }
  starts[g] = lo;
}

__global__ void k_final(const float* __restrict__ pool, const int* __restrict__ starts,
                        const float* __restrict__ gamma, const float* __restrict__ beta,
                        float* __restrict__ out) {
  __shared__ float2 red[256];
  int g = blockIdx.x, ch = threadIdx.x;
  int cnt = starts[g + 1] - starts[g];
  float p = pool[g * 256 + ch] / fmaxf((float)cnt, 1.f);
  red[ch] = make_float2(p, p * p);
  __syncthreads();
  for (int off = 128; off > 0; off >>= 1) {
    if (ch < off) { red[ch].x += red[ch + off].x; red[ch].y += red[ch + off].y; }
    __syncthreads();
  }
  float mu = red[0].x * (1.f / 256.f);
  float var = red[0].y * (1.f / 256.f) - mu * mu;
  out[g * 256 + ch] = (p - mu) * rsqrtf(var + 1e-5f) * gamma[ch] + beta[ch];
}

extern "C" void kernel_launch(void* const* d_in, const int* in_sizes, int n_in,
                              void* d_out, int out_size, void* d_ws, size_t ws_size,
                              hipStream_t stream) {
  const float* x     = (const float*)d_in[0];
  const int*   ei    = (const int*)d_in[1];
  const int*   batch = (const int*)d_in[2];
  const float* W11 = (const float*)d_in[3];  const float* b11 = (const float*)d_in[4];
  const float* W12 = (const float*)d_in[5];  const float* b12 = (const float*)d_in[6];
  const float* W21 = (const float*)d_in[7];  const float* b21 = (const float*)d_in[8];
  const float* W22 = (const float*)d_in[9];  const float* b22 = (const float*)d_in[10];
  const float* gamma = (const float*)d_in[11];
  const float* beta  = (const float*)d_in[12];
  float* out = (float*)d_out;

  int n = in_sizes[0] / 128;   // 100000
  int e = in_sizes[1] / 2;     // 1600000
  const int* src = ei;
  const int* dstv = ei + e;

  int NB = (n + 511) >> 9;                 // 196 buckets
  int NW = (e + CHUNKC - 1) / CHUNKC;      // 200 workgroups
  int NS = NB * NW;                        // 39200 scan entries

  char* ws = (char*)d_ws;
  auto alloc = [&](size_t bytes) { char* p = ws; ws += (bytes + 15) & ~(size_t)15; return p; };
  _Float16* P0 = (_Float16*)alloc((size_t)(n + 1) * 128 * 2);  // +1: pad row for agg/mlp OOB
  _Float16* P1 = (_Float16*)alloc((size_t)(n + 1) * 128 * 2);
  float* pool  = (float*)alloc((size_t)GRAPHS * 256 * 4);
  int* ptr     = (int*)alloc((size_t)(n + 1) * 4);
  int* csr     = (int*)alloc((size_t)e * 4);
  int* part    = (int*)alloc((size_t)e * 4);
  int* histG   = (int*)alloc((size_t)NS * 4);
  int* off     = (int*)alloc((size_t)NS * 4);
  int* bsum    = (int*)alloc(256 * 4);
  int* starts  = (int*)alloc((GRAPHS + 1) * 4);
  _Float16* w11t = (_Float16*)alloc(128 * 128 * 2);
  _Float16* w12t = (_Float16*)alloc(128 * 128 * 2);
  _Float16* w21t = (_Float16*)alloc(128 * 128 * 2);
  _Float16* w22t = (_Float16*)alloc(256 * 128 * 2);

  hipMemsetAsync(pool, 0, (size_t)GRAPHS * 256 * 4, stream);
  hipMemsetAsync(P0 + (size_t)n * 128, 0, 256, stream);   // zero pad row
  hipMemsetAsync(P1 + (size_t)n * 128, 0, 256, stream);   // zero pad row (mlp OOB reads)

  int nbk = (NS + 1023) / 1024;            // 39 scan blocks
  k_hist <<<NW, 256, 0, stream>>>(dstv, histG, e, NB, NW);
  k_scanA<<<nbk, 256, 0, stream>>>(histG, off, bsum, NS);
  k_scanB<<<1, 256, 0, stream>>>(bsum, nbk);
  k_scanC<<<(NS + 255) / 256, 256, 0, stream>>>(off, bsum, NS);
  k_part <<<NW, 256, 0, stream>>>(src, dstv, histG, off, part, e, NB, NW);
  k_csrb <<<NB, 256, 0, stream>>>(part, off, ptr, csr, e, NB, NW, n);
  k_starts<<<1, 256, 0, stream>>>(batch, starts, n);
  k_wprep_all<<<640, 128, 0, stream>>>(W11, W12, W21, W22, w11t, w12t, w21t, w22t);
  k_cvt<<<(n * 32 + 255) / 256, 256, 0, stream>>>(x, P0, n * 32);

  int mb = (n + 127) / 128;                // 782 MLP tiles
  int ab = (n * 64 + 255) / 256;

  k_agg_h<<<ab, 256, 0, stream>>>(P0, P1, ptr, csr, n);                    // P1 = x + agg(x)
  k_mlp128<<<mb, 256, 0, stream>>>(P1, w11t, b11, w12t, b12, P0, n);       // P0 = h1
  k_agg_h<<<ab, 256, 0, stream>>>(P0, P1, ptr, csr, n);                    // P1 = h1 + agg(h1)
  k_mlp_pool<<<mb, 256, 0, stream>>>(P1, w21t, b21, w22t, b22, batch, pool, n);
  k_final<<<GRAPHS, 256, 0, stream>>>(pool, starts, gamma, beta, out);
}

// Round 10
// 309.410 us; speedup vs baseline: 1.1818x; 1.1818x over previous
//
#include <hip/hip_runtime.h>

#define GRAPHS 128
#define CHUNKC 8000

typedef _Float16 f16x8 __attribute__((ext_vector_type(8)));
typedef _Float16 f16x4 __attribute__((ext_vector_type(4)));
typedef _Float16 f16x2 __attribute__((ext_vector_type(2)));
typedef float f32x4 __attribute__((ext_vector_type(4)));

// ============ CSR build: bucket counting sort, XCD-local writes ============
__global__ void k_hist(const int* __restrict__ dst, int* __restrict__ histG,
                       int e, int NB, int NW) {
  __shared__ int h[256];
  int t = threadIdx.x, w = blockIdx.x;
  h[t] = 0; __syncthreads();
  int lo = w * CHUNKC, hi = min(lo + CHUNKC, e);
  for (int i = lo + t; i < hi; i += 256) atomicAdd(&h[dst[i] >> 9], 1);
  __syncthreads();
  if (t < NB) histG[t * NW + w] = h[t];
}

// ---- 3-phase parallel exclusive scan of N ints ----
__global__ void k_scanA(const int* __restrict__ in, int* __restrict__ out,
                        int* __restrict__ bsum, int N) {
  __shared__ int s[256];
  int t = threadIdx.x, b = blockIdx.x;
  int base = b * 1024 + t * 4;
  int v[4]; int tot = 0;
#pragma unroll
  for (int j = 0; j < 4; ++j) { int i = base + j; v[j] = (i < N) ? in[i] : 0; tot += v[j]; }
  s[t] = tot; __syncthreads();
  for (int o = 1; o < 256; o <<= 1) {
    int x = (t >= o) ? s[t - o] : 0;
    __syncthreads(); s[t] += x; __syncthreads();
  }
  int run = s[t] - tot;
#pragma unroll
  for (int j = 0; j < 4; ++j) { int i = base + j; if (i < N) out[i] = run; run += v[j]; }
  if (t == 255) bsum[b] = s[255];
}

__global__ void k_scanB(int* bsum, int nb) {  // 1 block, nb <= 256
  __shared__ int s[256];
  int t = threadIdx.x;
  int v = (t < nb) ? bsum[t] : 0;
  s[t] = v; __syncthreads();
  for (int o = 1; o < 256; o <<= 1) {
    int x = (t >= o) ? s[t - o] : 0;
    __syncthreads(); s[t] += x; __syncthreads();
  }
  if (t < nb) bsum[t] = s[t] - v;
}

__global__ void k_scanC(int* __restrict__ out, const int* __restrict__ bsum, int N) {
  int i = blockIdx.x * 256 + threadIdx.x;
  if (i < N) out[i] += bsum[i >> 10];
}

__global__ void k_part(const int* __restrict__ src, const int* __restrict__ dst,
                       const int* __restrict__ histG, const int* __restrict__ off,
                       int* __restrict__ part, int e, int NB, int NW) {
  __shared__ int hist[256], lbA[256], lbB[256], stmp[256];
  __shared__ int els[CHUNKC];
  int t = threadIdx.x, w = blockIdx.x;
  int hv = (t < NB) ? histG[t * NW + w] : 0;
  hist[t] = hv; stmp[t] = hv; __syncthreads();
  for (int o = 1; o < 256; o <<= 1) {
    int x = (t >= o) ? stmp[t - o] : 0;
    __syncthreads(); stmp[t] += x; __syncthreads();
  }
  lbA[t] = stmp[t] - hv; lbB[t] = stmp[t] - hv;
  __syncthreads();
  int lo = w * CHUNKC, hi = min(lo + CHUNKC, e);
  for (int i = lo + t; i < hi; i += 256) {
    int d = dst[i];
    int p = atomicAdd(&lbB[d >> 9], 1);
    els[p] = src[i] | ((d & 511) << 17);   // src < 2^17, dstlow < 2^9
  }
  __syncthreads();
  int ln = t & 63, wv = t >> 6;
  for (int b = wv; b < NB; b += 4) {
    int c = hist[b], lb = lbA[b];
    long g = off[b * NW + w];
    for (int j = ln; j < c; j += 64) part[g + j] = els[lb + j];
  }
}

__global__ void k_csrb(const int* __restrict__ part, const int* __restrict__ off,
                       int* __restrict__ ptr, int* __restrict__ csr,
                       int e, int NB, int NW, int n) {
  __shared__ int nh[512], ncur[512], stmp[256];
  int t = threadIdx.x, b = blockIdx.x;
  int s0 = off[b * NW];
  int e0 = (b + 1 < NB) ? off[(b + 1) * NW] : e;
  nh[t] = 0; nh[t + 256] = 0; __syncthreads();
  for (int i = s0 + t; i < e0; i += 256) atomicAdd(&nh[((unsigned)part[i]) >> 17], 1);
  __syncthreads();
  int v0 = nh[2 * t], v1 = nh[2 * t + 1];
  int ps = v0 + v1;
  stmp[t] = ps; __syncthreads();
  for (int o = 1; o < 256; o <<= 1) {
    int x = (t >= o) ? stmp[t - o] : 0;
    __syncthreads(); stmp[t] += x; __syncthreads();
  }
  int base = stmp[t] - ps;
  __syncthreads();
  nh[2 * t] = base;   nh[2 * t + 1] = base + v0;
  ncur[2 * t] = base; ncur[2 * t + 1] = base + v0;
  __syncthreads();
#pragma unroll
  for (int q = 0; q < 2; ++q) {
    int vv = t + q * 256;
    int node = (b << 9) + vv;
    if (node <= n) ptr[node] = s0 + nh[vv];   // covers sentinel ptr[n]=e
  }
  for (int i = s0 + t; i < e0; i += 256) {
    int u = part[i];
    int p = atomicAdd(&ncur[((unsigned)u) >> 17], 1);
    csr[s0 + p] = u & 0x1FFFF;
  }
}

// ---------------- fp32 -> f16 conversion (x only) ----------------
__global__ void k_cvt(const float* __restrict__ in, _Float16* __restrict__ out, int total4) {
  int i = blockIdx.x * 256 + threadIdx.x;
  if (i >= total4) return;
  float4 v = ((const float4*)in)[i];
  f16x4 h = { (_Float16)v.x, (_Float16)v.y, (_Float16)v.z, (_Float16)v.w };
  ((f16x4*)out)[i] = h;
}

// ------------- aggregation: out[i] = in[i] + sum_N in[j], f16, f32 accum -------------
__global__ void k_agg_h(const _Float16* __restrict__ in, _Float16* __restrict__ out,
                        const int* __restrict__ ptr, const int* __restrict__ csr, int n) {
  int gid = blockIdx.x * 256 + threadIdx.x;
  int node = gid >> 6, lane = gid & 63;
  if (node >= n) return;
  const f16x8* inp = (const f16x8*)in;
  int cb = lane & 15, rg = lane >> 4;
  f16x8 self = inp[(size_t)node * 16 + cb];
  float acc[8];
#pragma unroll
  for (int c = 0; c < 8; ++c) acc[c] = (rg == 0) ? (float)self[c] : 0.f;
  int s = ptr[node], deg = ptr[node + 1] - s;
  for (int seg = 0; seg < deg; seg += 64) {
    int my = (seg + lane < deg) ? csr[s + seg + lane] : n;
    int segn = min(deg - seg, 64);
    for (int b2 = 0; b2 < segn; b2 += 32) {
      int jj[8]; f16x8 w[8];
#pragma unroll
      for (int u = 0; u < 8; ++u) jj[u] = __shfl(my, b2 + u * 4 + rg);
#pragma unroll
      for (int u = 0; u < 8; ++u) w[u] = inp[(size_t)jj[u] * 16 + cb];
#pragma unroll
      for (int u = 0; u < 8; ++u)
#pragma unroll
        for (int c = 0; c < 8; ++c) acc[c] += (float)w[u][c];
    }
  }
#pragma unroll
  for (int c = 0; c < 8; ++c) {
    acc[c] += __shfl_xor(acc[c], 16);
    acc[c] += __shfl_xor(acc[c], 32);
  }
  if (rg == 0) {
    f16x8 r;
#pragma unroll
    for (int c = 0; c < 8; ++c) r[c] = (_Float16)acc[c];
    ((f16x8*)out)[(size_t)node * 16 + cb] = r;
  }
}

// -------- weight prep: W[k][C] fp32 -> MFMA fragment order [kk][fc][lane][8] f16 --------
// frag value at ((kk*FCN+fc)*64+lane)*8+b  =  W[kk*32+(lane>>4)*8+b][fc*16+(lane&15)]
__global__ void k_wprep_all(const float* __restrict__ W11, const float* __restrict__ W12,
                            const float* __restrict__ W21, const float* __restrict__ W22,
                            f16x8* __restrict__ f11, f16x8* __restrict__ f12,
                            f16x8* __restrict__ f21, f16x8* __restrict__ f22) {
  int id = blockIdx.x * 256 + threadIdx.x;
  const float* W; f16x8* F; int C, cid, fshift;
  if (id < 2048)       { W = W11; F = f11; C = 128; cid = id;        fshift = 3; }
  else if (id < 4096)  { W = W12; F = f12; C = 128; cid = id - 2048; fshift = 3; }
  else if (id < 6144)  { W = W21; F = f21; C = 128; cid = id - 4096; fshift = 3; }
  else if (id < 10240) { W = W22; F = f22; C = 256; cid = id - 6144; fshift = 4; }
  else return;
  int lane = cid & 63;
  int rest = cid >> 6;
  int fc = rest & ((1 << fshift) - 1);
  int kk = rest >> fshift;
  int cout = fc * 16 + (lane & 15);
  int kb = kk * 32 + (lane >> 4) * 8;
  f16x8 v;
#pragma unroll
  for (int b = 0; b < 8; ++b) v[b] = (_Float16)W[(size_t)(kb + b) * C + cout];
  F[cid] = v;
}

// ---- in-register fragment transpose: lane(rg,l16) holds row l16 col-quads
//      {base+rg*4..+3} of frags aE(cols 0-15), aO(cols 16-31) ->
//      returns f16x8 = row l16, cols rg*8..rg*8+7  (4-lane-group shfl_xor) ----
__device__ __forceinline__ f16x8 xpose(f32x4 aE, f32x4 aO, int rg) {
  union U2 { _Float16 h[2]; int i; };
  union U8 { int i[4]; f16x8 v; };
  U2 e01, e23, o01, o23;
  e01.h[0] = (_Float16)aE[0]; e01.h[1] = (_Float16)aE[1];
  e23.h[0] = (_Float16)aE[2]; e23.h[1] = (_Float16)aE[3];
  o01.h[0] = (_Float16)aO[0]; o01.h[1] = (_Float16)aO[1];
  o23.h[0] = (_Float16)aO[2]; o23.h[1] = (_Float16)aO[3];
  int e01x1 = __shfl_xor(e01.i, 16), e01x2 = __shfl_xor(e01.i, 32), e01x3 = __shfl_xor(e01.i, 48);
  int e23x1 = __shfl_xor(e23.i, 16), e23x2 = __shfl_xor(e23.i, 32), e23x3 = __shfl_xor(e23.i, 48);
  int o01x1 = __shfl_xor(o01.i, 16), o01x2 = __shfl_xor(o01.i, 32), o01x3 = __shfl_xor(o01.i, 48);
  int o23x1 = __shfl_xor(o23.i, 16), o23x2 = __shfl_xor(o23.i, 32), o23x3 = __shfl_xor(o23.i, 48);
  U8 r;
  r.i[0] = rg == 0 ? e01.i : rg == 1 ? e01x3 : rg == 2 ? o01x2 : o01x1;
  r.i[1] = rg == 0 ? e23.i : rg == 1 ? e23x3 : rg == 2 ? o23x2 : o23x1;
  r.i[2] = rg == 0 ? e01x1 : rg == 1 ? e01x2 : rg == 2 ? o01x3 : o01.i;
  r.i[3] = rg == 0 ? e23x1 : rg == 1 ? e23x2 : rg == 2 ? o23x3 : o23.i;
  return r.v;
}

// ------- fused MLP: out = relu(relu(in@WA+bA)@WB+bB), 128->128->128 -------
// Both layers TRANSPOSED (mfma(Wfrag, xfrag)); h and out rebuilt in registers
// via xpose; weights in one reused 32KB LDS buffer (lane-linear, conflict-free);
// x from global (prefetchable streaming). 128 rows, 256 thr.
__launch_bounds__(256, 3)
__global__ void k_mlp128(const _Float16* __restrict__ in, const f16x8* __restrict__ wfA,
                         const float* __restrict__ bA, const f16x8* __restrict__ wfB,
                         const float* __restrict__ bB, _Float16* __restrict__ out, int n) {
  __shared__ f16x8 wf[2048];   // 32 KB, holds WA frags then WB frags
  int t = threadIdx.x;
  int r0 = blockIdx.x * 128;
  int lane = t & 63, w = t >> 6;
  int l16 = lane & 15, rg = lane >> 4;
  int rw = w * 32;
  const f16x8* inp = (const f16x8*)in;
#pragma unroll
  for (int i = 0; i < 8; ++i) wf[t + i * 256] = wfA[t + i * 256];
  int ra0 = r0 + rw + l16;      if (ra0 > n) ra0 = n;   // row n = zero pad row
  int ra1 = r0 + rw + 16 + l16; if (ra1 > n) ra1 = n;
  f16x8 xf[2][4];
#pragma unroll
  for (int kk = 0; kk < 4; ++kk) {
    xf[0][kk] = inp[(size_t)ra0 * 16 + kk * 4 + rg];
    xf[1][kk] = inp[(size_t)ra1 * 16 + kk * 4 + rg];
  }
  __syncthreads();
  f32x4 acc[2][8];
#pragma unroll
  for (int rs = 0; rs < 2; ++rs)
#pragma unroll
    for (int fc = 0; fc < 8; ++fc) acc[rs][fc] = (f32x4){0.f, 0.f, 0.f, 0.f};
#pragma unroll
  for (int kk = 0; kk < 4; ++kk)
#pragma unroll
    for (int fc = 0; fc < 8; ++fc) {
      f16x8 a = wf[(kk * 8 + fc) * 64 + lane];
      acc[0][fc] = __builtin_amdgcn_mfma_f32_16x16x32_f16(a, xf[0][kk], acc[0][fc], 0, 0, 0);
      acc[1][fc] = __builtin_amdgcn_mfma_f32_16x16x32_f16(a, xf[1][kk], acc[1][fc], 0, 0, 0);
    }
  // bias + relu on quads (cols fc*16 + rg*4 + j), then xpose -> h frags
  f16x8 hf[2][4];
#pragma unroll
  for (int fc = 0; fc < 8; ++fc) {
    float4 bv = *(const float4*)(bA + fc * 16 + rg * 4);
#pragma unroll
    for (int rs = 0; rs < 2; ++rs) {
      acc[rs][fc][0] = fmaxf(acc[rs][fc][0] + bv.x, 0.f);
      acc[rs][fc][1] = fmaxf(acc[rs][fc][1] + bv.y, 0.f);
      acc[rs][fc][2] = fmaxf(acc[rs][fc][2] + bv.z, 0.f);
      acc[rs][fc][3] = fmaxf(acc[rs][fc][3] + bv.w, 0.f);
    }
  }
#pragma unroll
  for (int rs = 0; rs < 2; ++rs)
#pragma unroll
    for (int kk = 0; kk < 4; ++kk)
      hf[rs][kk] = xpose(acc[rs][2 * kk], acc[rs][2 * kk + 1], rg);
  __syncthreads();                       // all waves done reading WA frags
#pragma unroll
  for (int i = 0; i < 8; ++i) wf[t + i * 256] = wfB[t + i * 256];
  __syncthreads();
#pragma unroll
  for (int rs = 0; rs < 2; ++rs)
#pragma unroll
    for (int fc = 0; fc < 8; ++fc) acc[rs][fc] = (f32x4){0.f, 0.f, 0.f, 0.f};
#pragma unroll
  for (int kk = 0; kk < 4; ++kk)
#pragma unroll
    for (int fc = 0; fc < 8; ++fc) {
      f16x8 b = wf[(kk * 8 + fc) * 64 + lane];
      acc[0][fc] = __builtin_amdgcn_mfma_f32_16x16x32_f16(b, hf[0][kk], acc[0][fc], 0, 0, 0);
      acc[1][fc] = __builtin_amdgcn_mfma_f32_16x16x32_f16(b, hf[1][kk], acc[1][fc], 0, 0, 0);
    }
#pragma unroll
  for (int fc = 0; fc < 8; ++fc) {
    float4 bv = *(const float4*)(bB + fc * 16 + rg * 4);
#pragma unroll
    for (int rs = 0; rs < 2; ++rs) {
      acc[rs][fc][0] = fmaxf(acc[rs][fc][0] + bv.x, 0.f);
      acc[rs][fc][1] = fmaxf(acc[rs][fc][1] + bv.y, 0.f);
      acc[rs][fc][2] = fmaxf(acc[rs][fc][2] + bv.z, 0.f);
      acc[rs][fc][3] = fmaxf(acc[rs][fc][3] + bv.w, 0.f);
    }
  }
  f16x8* outp = (f16x8*)out;
#pragma unroll
  for (int rs = 0; rs < 2; ++rs) {
    int row = r0 + rw + rs * 16 + l16;
#pragma unroll
    for (int kk = 0; kk < 4; ++kk) {
      f16x8 o = xpose(acc[rs][2 * kk], acc[rs][2 * kk + 1], rg);
      if (row < n) outp[(size_t)row * 16 + kk * 4 + rg] = o;
    }
  }
}

// ------- fused MLP + pool: relu(relu(in@W21+b21)@W22+b22) summed per graph -------
// Layer 1 transposed + xpose (h in regs); layer 2 NORMAL orientation so the
// per-lane column/row-run pooling epilogue still applies.
__launch_bounds__(256, 3)
__global__ void k_mlp_pool(const _Float16* __restrict__ in, const f16x8* __restrict__ wfA,
                           const float* __restrict__ bA, const f16x8* __restrict__ wfB,
                           const float* __restrict__ bB, const int* __restrict__ batch,
                           float* __restrict__ pool, int n) {
  __shared__ f16x8 wf[2048];     // 32 KB
  __shared__ float pool_l[8 * 256];
  int t = threadIdx.x;
  int r0 = blockIdx.x * 128;
  int lane = t & 63, w = t >> 6;
  int l16 = lane & 15, rg = lane >> 4;
  int rw = w * 32;
  const f16x8* inp = (const f16x8*)in;
#pragma unroll
  for (int j = 0; j < 8; ++j) pool_l[j * 256 + t] = 0.f;
#pragma unroll
  for (int i = 0; i < 8; ++i) wf[t + i * 256] = wfA[t + i * 256];
  int ra0 = r0 + rw + l16;      if (ra0 > n) ra0 = n;
  int ra1 = r0 + rw + 16 + l16; if (ra1 > n) ra1 = n;
  f16x8 xf[2][4];
#pragma unroll
  for (int kk = 0; kk < 4; ++kk) {
    xf[0][kk] = inp[(size_t)ra0 * 16 + kk * 4 + rg];
    xf[1][kk] = inp[(size_t)ra1 * 16 + kk * 4 + rg];
  }
  int g0 = batch[r0];
  int rloc = rw + rg * 4;
  int g4[2][4];
#pragma unroll
  for (int fr = 0; fr < 2; ++fr)
#pragma unroll
    for (int j = 0; j < 4; ++j) {
      int row = r0 + rloc + fr * 16 + j;
      g4[fr][j] = (row < n) ? batch[row] : -1;
    }
  __syncthreads();
  f32x4 acc[2][8];
#pragma unroll
  for (int rs = 0; rs < 2; ++rs)
#pragma unroll
    for (int fc = 0; fc < 8; ++fc) acc[rs][fc] = (f32x4){0.f, 0.f, 0.f, 0.f};
#pragma unroll
  for (int kk = 0; kk < 4; ++kk)
#pragma unroll
    for (int fc = 0; fc < 8; ++fc) {
      f16x8 a = wf[(kk * 8 + fc) * 64 + lane];
      acc[0][fc] = __builtin_amdgcn_mfma_f32_16x16x32_f16(a, xf[0][kk], acc[0][fc], 0, 0, 0);
      acc[1][fc] = __builtin_amdgcn_mfma_f32_16x16x32_f16(a, xf[1][kk], acc[1][fc], 0, 0, 0);
    }
  f16x8 hf[2][4];
#pragma unroll
  for (int fc = 0; fc < 8; ++fc) {
    float4 bv = *(const float4*)(bA + fc * 16 + rg * 4);
#pragma unroll
    for (int rs = 0; rs < 2; ++rs) {
      acc[rs][fc][0] = fmaxf(acc[rs][fc][0] + bv.x, 0.f);
      acc[rs][fc][1] = fmaxf(acc[rs][fc][1] + bv.y, 0.f);
      acc[rs][fc][2] = fmaxf(acc[rs][fc][2] + bv.z, 0.f);
      acc[rs][fc][3] = fmaxf(acc[rs][fc][3] + bv.w, 0.f);
    }
  }
#pragma unroll
  for (int rs = 0; rs < 2; ++rs)
#pragma unroll
    for (int kk = 0; kk < 4; ++kk)
      hf[rs][kk] = xpose(acc[rs][2 * kk], acc[rs][2 * kk + 1], rg);
  // ---- layer 2 (W22, 256 cols): two 128-col halves, wf restaged per half
  for (int h = 0; h < 2; ++h) {
    __syncthreads();                       // prior wf reads complete
#pragma unroll
    for (int i = 0; i < 8; ++i) {
      int id = t + i * 256;                // 0..2047
      int lj = id & 63, fcl = (id >> 6) & 7, kk = id >> 9;
      wf[id] = wfB[(kk * 16 + h * 8 + fcl) * 64 + lj];
    }
    __syncthreads();
#pragma unroll
    for (int rs = 0; rs < 2; ++rs)
#pragma unroll
      for (int fc = 0; fc < 8; ++fc) acc[rs][fc] = (f32x4){0.f, 0.f, 0.f, 0.f};
#pragma unroll
    for (int kk = 0; kk < 4; ++kk)
#pragma unroll
      for (int fc = 0; fc < 8; ++fc) {
        f16x8 b = wf[(kk * 8 + fc) * 64 + lane];
        acc[0][fc] = __builtin_amdgcn_mfma_f32_16x16x32_f16(hf[0][kk], b, acc[0][fc], 0, 0, 0);
        acc[1][fc] = __builtin_amdgcn_mfma_f32_16x16x32_f16(hf[1][kk], b, acc[1][fc], 0, 0, 0);
      }
    // epilogue: lane holds 4 consecutive rows x fixed col -> run-compress
#pragma unroll
    for (int fc = 0; fc < 8; ++fc) {
      int col = h * 128 + fc * 16 + l16;
      float bv = bB[col];
#pragma unroll
      for (int fr = 0; fr < 2; ++fr) {
        f32x4 a = acc[fr][fc];
        float run = fmaxf(a[0] + bv, 0.f);
#pragma unroll
        for (int j = 1; j < 4; ++j) {
          float v = fmaxf(a[j] + bv, 0.f);
          if (g4[fr][j] == g4[fr][j - 1]) run += v;
          else {
            int g = g4[fr][j - 1];
            if (g >= 0) {
              int d = g - g0;
              if (d >= 0 && d < 8) atomicAdd(&pool_l[d * 256 + col], run);
              else atomicAdd(&pool[g * 256 + col], run);
            }
            run = v;
          }
        }
        int g = g4[fr][3];
        if (g >= 0) {
          int d = g - g0;
          if (d >= 0 && d < 8) atomicAdd(&pool_l[d * 256 + col], run);
          else atomicAdd(&pool[g * 256 + col], run);
        }
      }
    }
  }
  __syncthreads();
#pragma unroll
  for (int j = 0; j < 8; ++j) {
    int idx = j * 256 + t;
    int g = g0 + (idx >> 8), col = idx & 255;
    float v = pool_l[idx];
    if (g < GRAPHS && v != 0.f) atomicAdd(&pool[g * 256 + col], v);
  }
}

// ---------------- graph boundaries + LayerNorm finalize ----------------
__global__ void k_starts(const int* __restrict__ batch, int* __restrict__ starts, int n) {
  int g = threadIdx.x;
  if (g > GRAPHS) return;
  int lo = 0, hi = n;
  while (lo < hi) { int mid = (lo + hi) >> 1; if (batch[mid] < g) lo = mid + 1; else hi = mid; }
  starts[g] = lo;
}

__global__ void k_final(const float* __restrict__ pool, const int* __restrict__ starts,
                        const float* __restrict__ gamma, const float* __restrict__ beta,
                        float* __restrict__ out) {
  __shared__ float2 red[256];
  int g = blockIdx.x, ch = threadIdx.x;
  int cnt = starts[g + 1] - starts[g];
  float p = pool[g * 256 + ch] / fmaxf((float)cnt, 1.f);
  red[ch] = make_float2(p, p * p);
  __syncthreads();
  for (int off = 128; off > 0; off >>= 1) {
    if (ch < off) { red[ch].x += red[ch + off].x; red[ch].y += red[ch + off].y; }
    __syncthreads();
  }
  float mu = red[0].x * (1.f / 256.f);
  float var = red[0].y * (1.f / 256.f) - mu * mu;
  out[g * 256 + ch] = (p - mu) * rsqrtf(var + 1e-5f) * gamma[ch] + beta[ch];
}

extern "C" void kernel_launch(void* const* d_in, const int* in_sizes, int n_in,
                              void* d_out, int out_size, void* d_ws, size_t ws_size,
                              hipStream_t stream) {
  const float* x     = (const float*)d_in[0];
  const int*   ei    = (const int*)d_in[1];
  const int*   batch = (const int*)d_in[2];
  const float* W11 = (const float*)d_in[3];  const float* b11 = (const float*)d_in[4];
  const float* W12 = (const float*)d_in[5];  const float* b12 = (const float*)d_in[6];
  const float* W21 = (const float*)d_in[7];  const float* b21 = (const float*)d_in[8];
  const float* W22 = (const float*)d_in[9];  const float* b22 = (const float*)d_in[10];
  const float* gamma = (const float*)d_in[11];
  const float* beta  = (const float*)d_in[12];
  float* out = (float*)d_out;

  int n = in_sizes[0] / 128;   // 100000
  int e = in_sizes[1] / 2;     // 1600000
  const int* src = ei;
  const int* dstv = ei + e;

  int NB = (n + 511) >> 9;                 // 196 buckets
  int NW = (e + CHUNKC - 1) / CHUNKC;      // 200 workgroups
  int NS = NB * NW;                        // 39200 scan entries

  char* ws = (char*)d_ws;
  auto alloc = [&](size_t bytes) { char* p = ws; ws += (bytes + 15) & ~(size_t)15; return p; };
  _Float16* P0 = (_Float16*)alloc((size_t)(n + 1) * 128 * 2);  // +1: zero pad row
  _Float16* P1 = (_Float16*)alloc((size_t)(n + 1) * 128 * 2);
  float* pool  = (float*)alloc((size_t)GRAPHS * 256 * 4);
  int* ptr     = (int*)alloc((size_t)(n + 1) * 4);
  int* csr     = (int*)alloc((size_t)e * 4);
  int* part    = (int*)alloc((size_t)e * 4);
  int* histG   = (int*)alloc((size_t)NS * 4);
  int* off     = (int*)alloc((size_t)NS * 4);
  int* bsum    = (int*)alloc(256 * 4);
  int* starts  = (int*)alloc((GRAPHS + 1) * 4);
  f16x8* f11 = (f16x8*)alloc(2048 * 16);
  f16x8* f12 = (f16x8*)alloc(2048 * 16);
  f16x8* f21 = (f16x8*)alloc(2048 * 16);
  f16x8* f22 = (f16x8*)alloc(4096 * 16);

  hipMemsetAsync(pool, 0, (size_t)GRAPHS * 256 * 4, stream);
  hipMemsetAsync(P0 + (size_t)n * 128, 0, 256, stream);   // zero pad rows
  hipMemsetAsync(P1 + (size_t)n * 128, 0, 256, stream);

  int nbk = (NS + 1023) / 1024;            // 39 scan blocks
  k_hist <<<NW, 256, 0, stream>>>(dstv, histG, e, NB, NW);
  k_scanA<<<nbk, 256, 0, stream>>>(histG, off, bsum, NS);
  k_scanB<<<1, 256, 0, stream>>>(bsum, nbk);
  k_scanC<<<(NS + 255) / 256, 256, 0, stream>>>(off, bsum, NS);
  k_part <<<NW, 256, 0, stream>>>(src, dstv, histG, off, part, e, NB, NW);
  k_csrb <<<NB, 256, 0, stream>>>(part, off, ptr, csr, e, NB, NW, n);
  k_starts<<<1, 256, 0, stream>>>(batch, starts, n);
  k_wprep_all<<<40, 256, 0, stream>>>(W11, W12, W21, W22, f11, f12, f21, f22);
  k_cvt<<<(n * 32 + 255) / 256, 256, 0, stream>>>(x, P0, n * 32);

  int mb = (n + 127) / 128;                // 782 MLP tiles
  int ab = (n * 64 + 255) / 256;

  k_agg_h<<<ab, 256, 0, stream>>>(P0, P1, ptr, csr, n);               // P1 = x + agg(x)
  k_mlp128<<<mb, 256, 0, stream>>>(P1, f11, b11, f12, b12, P0, n);    // P0 = h1
  k_agg_h<<<ab, 256, 0, stream>>>(P0, P1, ptr, csr, n);               // P1 = h1 + agg(h1)
  k_mlp_pool<<<mb, 256, 0, stream>>>(P1, f21, b21, f22, b22, batch, pool, n);
  k_final<<<GRAPHS, 256, 0, stream>>>(pool, starts, gamma, beta, out);
}

// Round 11
// 282.117 us; speedup vs baseline: 1.2962x; 1.0967x over previous
//
#include <hip/hip_runtime.h>

#define GRAPHS 128
#define CHUNKC 4000

typedef _Float16 f16x8 __attribute__((ext_vector_type(8)));
typedef _Float16 f16x4 __attribute__((ext_vector_type(4)));
typedef _Float16 f16x2 __attribute__((ext_vector_type(2)));
typedef float f32x4 __attribute__((ext_vector_type(4)));

// v_fma_mix_f32: acc += (float)f16_half(w) in ONE VALU op (exact cvt+fma)
__device__ __forceinline__ void fmix_lo(float& a, int w) {
  asm("v_fma_mix_f32 %0, %1, 1.0, %0 op_sel:[0,0,0] op_sel_hi:[1,0,0]" : "+v"(a) : "v"(w));
}
__device__ __forceinline__ void fmix_hi(float& a, int w) {
  asm("v_fma_mix_f32 %0, %1, 1.0, %0 op_sel:[1,0,0] op_sel_hi:[1,0,0]" : "+v"(a) : "v"(w));
}

// ============ CSR build: bucket counting sort, XCD-local writes ============
__global__ void k_hist(const int* __restrict__ dst, int* __restrict__ histG,
                       int e, int NB, int NW) {
  __shared__ int h[256];
  int t = threadIdx.x, w = blockIdx.x;
  h[t] = 0; __syncthreads();
  int lo = w * CHUNKC, hi = min(lo + CHUNKC, e);
  for (int i = lo + t; i < hi; i += 256) atomicAdd(&h[dst[i] >> 9], 1);
  __syncthreads();
  if (t < NB) histG[t * NW + w] = h[t];
}

// ---- 3-phase parallel exclusive scan of N ints ----
__global__ void k_scanA(const int* __restrict__ in, int* __restrict__ out,
                        int* __restrict__ bsum, int N) {
  __shared__ int s[256];
  int t = threadIdx.x, b = blockIdx.x;
  int base = b * 1024 + t * 4;
  int v[4]; int tot = 0;
#pragma unroll
  for (int j = 0; j < 4; ++j) { int i = base + j; v[j] = (i < N) ? in[i] : 0; tot += v[j]; }
  s[t] = tot; __syncthreads();
  for (int o = 1; o < 256; o <<= 1) {
    int x = (t >= o) ? s[t - o] : 0;
    __syncthreads(); s[t] += x; __syncthreads();
  }
  int run = s[t] - tot;
#pragma unroll
  for (int j = 0; j < 4; ++j) { int i = base + j; if (i < N) out[i] = run; run += v[j]; }
  if (t == 255) bsum[b] = s[255];
}

// scan of block sums + (independent) graph-boundary binary search
__global__ void k_scanB(int* bsum, int nb, const int* __restrict__ batch,
                        int* __restrict__ starts, int n) {
  __shared__ int s[256];
  int t = threadIdx.x;
  int v = (t < nb) ? bsum[t] : 0;
  s[t] = v; __syncthreads();
  for (int o = 1; o < 256; o <<= 1) {
    int x = (t >= o) ? s[t - o] : 0;
    __syncthreads(); s[t] += x; __syncthreads();
  }
  if (t < nb) bsum[t] = s[t] - v;
  if (t <= GRAPHS) {
    int lo = 0, hi = n;
    while (lo < hi) { int mid = (lo + hi) >> 1; if (batch[mid] < t) lo = mid + 1; else hi = mid; }
    starts[t] = lo;
  }
}

__global__ void k_scanC(int* __restrict__ out, const int* __restrict__ bsum, int N) {
  int i = blockIdx.x * 256 + threadIdx.x;
  if (i < N) out[i] += bsum[i >> 10];
}

__global__ void k_part(const int* __restrict__ src, const int* __restrict__ dst,
                       const int* __restrict__ histG, const int* __restrict__ off,
                       int* __restrict__ part, int e, int NB, int NW) {
  __shared__ int hist[256], lbA[256], lbB[256], stmp[256];
  __shared__ int els[CHUNKC];
  int t = threadIdx.x, w = blockIdx.x;
  int hv = (t < NB) ? histG[t * NW + w] : 0;
  hist[t] = hv; stmp[t] = hv; __syncthreads();
  for (int o = 1; o < 256; o <<= 1) {
    int x = (t >= o) ? stmp[t - o] : 0;
    __syncthreads(); stmp[t] += x; __syncthreads();
  }
  lbA[t] = stmp[t] - hv; lbB[t] = stmp[t] - hv;
  __syncthreads();
  int lo = w * CHUNKC, hi = min(lo + CHUNKC, e);
  for (int i = lo + t; i < hi; i += 256) {
    int d = dst[i];
    int p = atomicAdd(&lbB[d >> 9], 1);
    els[p] = src[i] | ((d & 511) << 17);   // src < 2^17, dstlow < 2^9
  }
  __syncthreads();
  int ln = t & 63, wv = t >> 6;
  for (int b = wv; b < NB; b += 4) {
    int c = hist[b], lb = lbA[b];
    long g = off[b * NW + w];
    for (int j = ln; j < c; j += 64) part[g + j] = els[lb + j];
  }
}

__global__ void k_csrb(const int* __restrict__ part, const int* __restrict__ off,
                       int* __restrict__ ptr, int* __restrict__ csr,
                       int e, int NB, int NW, int n) {
  __shared__ int nh[512], ncur[512], stmp[256];
  int t = threadIdx.x, b = blockIdx.x;
  int s0 = off[b * NW];
  int e0 = (b + 1 < NB) ? off[(b + 1) * NW] : e;
  nh[t] = 0; nh[t + 256] = 0; __syncthreads();
  for (int i = s0 + t; i < e0; i += 256) atomicAdd(&nh[((unsigned)part[i]) >> 17], 1);
  __syncthreads();
  int v0 = nh[2 * t], v1 = nh[2 * t + 1];
  int ps = v0 + v1;
  stmp[t] = ps; __syncthreads();
  for (int o = 1; o < 256; o <<= 1) {
    int x = (t >= o) ? stmp[t - o] : 0;
    __syncthreads(); stmp[t] += x; __syncthreads();
  }
  int base = stmp[t] - ps;
  __syncthreads();
  nh[2 * t] = base;   nh[2 * t + 1] = base + v0;
  ncur[2 * t] = base; ncur[2 * t + 1] = base + v0;
  __syncthreads();
#pragma unroll
  for (int q = 0; q < 2; ++q) {
    int vv = t + q * 256;
    int node = (b << 9) + vv;
    if (node <= n) ptr[node] = s0 + nh[vv];   // covers sentinel ptr[n]=e
  }
  for (int i = s0 + t; i < e0; i += 256) {
    int u = part[i];
    int p = atomicAdd(&ncur[((unsigned)u) >> 17], 1);
    csr[s0 + p] = u & 0x1FFFF;
  }
}

// -------- combined prep: x cvt fp32->f16, weight frag prep, pool zero, pad rows --------
// frag value at ((kk*FCN+fc)*64+lane)*8+b  =  W[kk*32+(lane>>4)*8+b][fc*16+(lane&15)]
__global__ void k_prep(const float* __restrict__ x, _Float16* __restrict__ P0,
                       _Float16* __restrict__ P1, int n,
                       const float* __restrict__ W11, const float* __restrict__ W12,
                       const float* __restrict__ W21, const float* __restrict__ W22,
                       f16x8* __restrict__ f11, f16x8* __restrict__ f12,
                       f16x8* __restrict__ f21, f16x8* __restrict__ f22,
                       float* __restrict__ pool, int cvtb, int wpb, int poolb) {
  int b = blockIdx.x, t = threadIdx.x;
  if (b < cvtb) {                         // x conversion (f16x4 granules)
    int i = b * 256 + t;
    if (i < n * 32) {
      float4 v = ((const float4*)x)[i];
      f16x4 h = { (_Float16)v.x, (_Float16)v.y, (_Float16)v.z, (_Float16)v.w };
      ((f16x4*)P0)[i] = h;
    }
    return;
  }
  b -= cvtb;
  if (b < wpb) {                          // weight fragment prep
    int id = b * 256 + t;
    const float* W; f16x8* F; int C, cid, fshift;
    if (id < 2048)       { W = W11; F = f11; C = 128; cid = id;        fshift = 3; }
    else if (id < 4096)  { W = W12; F = f12; C = 128; cid = id - 2048; fshift = 3; }
    else if (id < 6144)  { W = W21; F = f21; C = 128; cid = id - 4096; fshift = 3; }
    else if (id < 10240) { W = W22; F = f22; C = 256; cid = id - 6144; fshift = 4; }
    else return;
    int lane = cid & 63;
    int rest = cid >> 6;
    int fc = rest & ((1 << fshift) - 1);
    int kk = rest >> fshift;
    int cout = fc * 16 + (lane & 15);
    int kb = kk * 32 + (lane >> 4) * 8;
    f16x8 v;
#pragma unroll
    for (int q = 0; q < 8; ++q) v[q] = (_Float16)W[(size_t)(kb + q) * C + cout];
    F[cid] = v;
    return;
  }
  b -= wpb;
  if (b < poolb) {                        // pool zero
    int i = b * 256 + t;
    if (i < GRAPHS * 256) pool[i] = 0.f;
    return;
  }
  // pad rows (row n) of P0/P1
  if (t < 128) P0[(size_t)n * 128 + t] = (_Float16)0.f;
  else P1[(size_t)n * 128 + (t - 128)] = (_Float16)0.f;
}

// ------------- aggregation: out[i] = in[i] + sum_N in[j], f16, f32 accum -------------
// wide gather (4 rows/instr, 32 rows in flight) + v_fma_mix accumulate
__global__ void k_agg_h(const _Float16* __restrict__ in, _Float16* __restrict__ out,
                        const int* __restrict__ ptr, const int* __restrict__ csr, int n) {
  int gid = blockIdx.x * 256 + threadIdx.x;
  int node = gid >> 6, lane = gid & 63;
  if (node >= n) return;
  const f16x8* inp = (const f16x8*)in;
  int cb = lane & 15, rg = lane >> 4;
  f16x8 self = inp[(size_t)node * 16 + cb];
  float acc[8];
#pragma unroll
  for (int c = 0; c < 8; ++c) acc[c] = (rg == 0) ? (float)self[c] : 0.f;
  int s = ptr[node], deg = ptr[node + 1] - s;
  union W { f16x8 v; int i[4]; };
  for (int seg = 0; seg < deg; seg += 64) {
    int my = (seg + lane < deg) ? csr[s + seg + lane] : n;
    int segn = min(deg - seg, 64);
    for (int b2 = 0; b2 < segn; b2 += 32) {
      int jj[8]; W w[8];
#pragma unroll
      for (int u = 0; u < 8; ++u) jj[u] = __shfl(my, b2 + u * 4 + rg);
#pragma unroll
      for (int u = 0; u < 8; ++u) w[u].v = inp[(size_t)jj[u] * 16 + cb];
#pragma unroll
      for (int u = 0; u < 8; ++u)
#pragma unroll
        for (int p = 0; p < 4; ++p) {
          fmix_lo(acc[2 * p], w[u].i[p]);
          fmix_hi(acc[2 * p + 1], w[u].i[p]);
        }
    }
  }
#pragma unroll
  for (int c = 0; c < 8; ++c) {
    acc[c] += __shfl_xor(acc[c], 16);
    acc[c] += __shfl_xor(acc[c], 32);
  }
  if (rg == 0) {
    f16x8 r;
#pragma unroll
    for (int c = 0; c < 8; ++c) r[c] = (_Float16)acc[c];
    ((f16x8*)out)[(size_t)node * 16 + cb] = r;
  }
}

// ---- in-register fragment transpose (4-lane-group shfl_xor) ----
__device__ __forceinline__ f16x8 xpose(f32x4 aE, f32x4 aO, int rg) {
  union U2 { _Float16 h[2]; int i; };
  union U8 { int i[4]; f16x8 v; };
  U2 e01, e23, o01, o23;
  e01.h[0] = (_Float16)aE[0]; e01.h[1] = (_Float16)aE[1];
  e23.h[0] = (_Float16)aE[2]; e23.h[1] = (_Float16)aE[3];
  o01.h[0] = (_Float16)aO[0]; o01.h[1] = (_Float16)aO[1];
  o23.h[0] = (_Float16)aO[2]; o23.h[1] = (_Float16)aO[3];
  int e01x1 = __shfl_xor(e01.i, 16), e01x2 = __shfl_xor(e01.i, 32), e01x3 = __shfl_xor(e01.i, 48);
  int e23x1 = __shfl_xor(e23.i, 16), e23x2 = __shfl_xor(e23.i, 32), e23x3 = __shfl_xor(e23.i, 48);
  int o01x1 = __shfl_xor(o01.i, 16), o01x2 = __shfl_xor(o01.i, 32), o01x3 = __shfl_xor(o01.i, 48);
  int o23x1 = __shfl_xor(o23.i, 16), o23x2 = __shfl_xor(o23.i, 32), o23x3 = __shfl_xor(o23.i, 48);
  U8 r;
  r.i[0] = rg == 0 ? e01.i : rg == 1 ? e01x3 : rg == 2 ? o01x2 : o01x1;
  r.i[1] = rg == 0 ? e23.i : rg == 1 ? e23x3 : rg == 2 ? o23x2 : o23x1;
  r.i[2] = rg == 0 ? e01x1 : rg == 1 ? e01x2 : rg == 2 ? o01x3 : o01.i;
  r.i[3] = rg == 0 ? e23x1 : rg == 1 ? e23x2 : rg == 2 ? o23x3 : o23.i;
  return r.v;
}

// ------- fused MLP: out = relu(relu(in@WA+bA)@WB+bB), 128->128->128 -------
__launch_bounds__(256, 3)
__global__ void k_mlp128(const _Float16* __restrict__ in, const f16x8* __restrict__ wfA,
                         const float* __restrict__ bA, const f16x8* __restrict__ wfB,
                         const float* __restrict__ bB, _Float16* __restrict__ out, int n) {
  __shared__ f16x8 wf[2048];   // 32 KB, holds WA frags then WB frags
  int t = threadIdx.x;
  int r0 = blockIdx.x * 128;
  int lane = t & 63, w = t >> 6;
  int l16 = lane & 15, rg = lane >> 4;
  int rw = w * 32;
  const f16x8* inp = (const f16x8*)in;
#pragma unroll
  for (int i = 0; i < 8; ++i) wf[t + i * 256] = wfA[t + i * 256];
  int ra0 = r0 + rw + l16;      if (ra0 > n) ra0 = n;   // row n = zero pad row
  int ra1 = r0 + rw + 16 + l16; if (ra1 > n) ra1 = n;
  f16x8 xf[2][4];
#pragma unroll
  for (int kk = 0; kk < 4; ++kk) {
    xf[0][kk] = inp[(size_t)ra0 * 16 + kk * 4 + rg];
    xf[1][kk] = inp[(size_t)ra1 * 16 + kk * 4 + rg];
  }
  __syncthreads();
  f32x4 acc[2][8];
#pragma unroll
  for (int rs = 0; rs < 2; ++rs)
#pragma unroll
    for (int fc = 0; fc < 8; ++fc) acc[rs][fc] = (f32x4){0.f, 0.f, 0.f, 0.f};
#pragma unroll
  for (int kk = 0; kk < 4; ++kk)
#pragma unroll
    for (int fc = 0; fc < 8; ++fc) {
      f16x8 a = wf[(kk * 8 + fc) * 64 + lane];
      acc[0][fc] = __builtin_amdgcn_mfma_f32_16x16x32_f16(a, xf[0][kk], acc[0][fc], 0, 0, 0);
      acc[1][fc] = __builtin_amdgcn_mfma_f32_16x16x32_f16(a, xf[1][kk], acc[1][fc], 0, 0, 0);
    }
  f16x8 hf[2][4];
#pragma unroll
  for (int fc = 0; fc < 8; ++fc) {
    float4 bv = *(const float4*)(bA + fc * 16 + rg * 4);
#pragma unroll
    for (int rs = 0; rs < 2; ++rs) {
      acc[rs][fc][0] = fmaxf(acc[rs][fc][0] + bv.x, 0.f);
      acc[rs][fc][1] = fmaxf(acc[rs][fc][1] + bv.y, 0.f);
      acc[rs][fc][2] = fmaxf(acc[rs][fc][2] + bv.z, 0.f);
      acc[rs][fc][3] = fmaxf(acc[rs][fc][3] + bv.w, 0.f);
    }
  }
#pragma unroll
  for (int rs = 0; rs < 2; ++rs)
#pragma unroll
    for (int kk = 0; kk < 4; ++kk)
      hf[rs][kk] = xpose(acc[rs][2 * kk], acc[rs][2 * kk + 1], rg);
  __syncthreads();                       // all waves done reading WA frags
#pragma unroll
  for (int i = 0; i < 8; ++i) wf[t + i * 256] = wfB[t + i * 256];
  __syncthreads();
#pragma unroll
  for (int rs = 0; rs < 2; ++rs)
#pragma unroll
    for (int fc = 0; fc < 8; ++fc) acc[rs][fc] = (f32x4){0.f, 0.f, 0.f, 0.f};
#pragma unroll
  for (int kk = 0; kk < 4; ++kk)
#pragma unroll
    for (int fc = 0; fc < 8; ++fc) {
      f16x8 b = wf[(kk * 8 + fc) * 64 + lane];
      acc[0][fc] = __builtin_amdgcn_mfma_f32_16x16x32_f16(b, hf[0][kk], acc[0][fc], 0, 0, 0);
      acc[1][fc] = __builtin_amdgcn_mfma_f32_16x16x32_f16(b, hf[1][kk], acc[1][fc], 0, 0, 0);
    }
#pragma unroll
  for (int fc = 0; fc < 8; ++fc) {
    float4 bv = *(const float4*)(bB + fc * 16 + rg * 4);
#pragma unroll
    for (int rs = 0; rs < 2; ++rs) {
      acc[rs][fc][0] = fmaxf(acc[rs][fc][0] + bv.x, 0.f);
      acc[rs][fc][1] = fmaxf(acc[rs][fc][1] + bv.y, 0.f);
      acc[rs][fc][2] = fmaxf(acc[rs][fc][2] + bv.z, 0.f);
      acc[rs][fc][3] = fmaxf(acc[rs][fc][3] + bv.w, 0.f);
    }
  }
  f16x8* outp = (f16x8*)out;
#pragma unroll
  for (int rs = 0; rs < 2; ++rs) {
    int row = r0 + rw + rs * 16 + l16;
#pragma unroll
    for (int kk = 0; kk < 4; ++kk) {
      f16x8 o = xpose(acc[rs][2 * kk], acc[rs][2 * kk + 1], rg);
      if (row < n) outp[(size_t)row * 16 + kk * 4 + rg] = o;
    }
  }
}

// ------- fused MLP + pool: relu(relu(in@W21+b21)@W22+b22) summed per graph -------
__launch_bounds__(256, 3)
__global__ void k_mlp_pool(const _Float16* __restrict__ in, const f16x8* __restrict__ wfA,
                           const float* __restrict__ bA, const f16x8* __restrict__ wfB,
                           const float* __restrict__ bB, const int* __restrict__ batch,
                           float* __restrict__ pool, int n) {
  __shared__ f16x8 wf[2048];     // 32 KB
  __shared__ float pool_l[8 * 256];
  int t = threadIdx.x;
  int r0 = blockIdx.x * 128;
  int lane = t & 63, w = t >> 6;
  int l16 = lane & 15, rg = lane >> 4;
  int rw = w * 32;
  const f16x8* inp = (const f16x8*)in;
#pragma unroll
  for (int j = 0; j < 8; ++j) pool_l[j * 256 + t] = 0.f;
#pragma unroll
  for (int i = 0; i < 8; ++i) wf[t + i * 256] = wfA[t + i * 256];
  int ra0 = r0 + rw + l16;      if (ra0 > n) ra0 = n;
  int ra1 = r0 + rw + 16 + l16; if (ra1 > n) ra1 = n;
  f16x8 xf[2][4];
#pragma unroll
  for (int kk = 0; kk < 4; ++kk) {
    xf[0][kk] = inp[(size_t)ra0 * 16 + kk * 4 + rg];
    xf[1][kk] = inp[(size_t)ra1 * 16 + kk * 4 + rg];
  }
  int g0 = batch[r0];
  int rloc = rw + rg * 4;
  int g4[2][4];
#pragma unroll
  for (int fr = 0; fr < 2; ++fr)
#pragma unroll
    for (int j = 0; j < 4; ++j) {
      int row = r0 + rloc + fr * 16 + j;
      g4[fr][j] = (row < n) ? batch[row] : -1;
    }
  __syncthreads();
  f32x4 acc[2][8];
#pragma unroll
  for (int rs = 0; rs < 2; ++rs)
#pragma unroll
    for (int fc = 0; fc < 8; ++fc) acc[rs][fc] = (f32x4){0.f, 0.f, 0.f, 0.f};
#pragma unroll
  for (int kk = 0; kk < 4; ++kk)
#pragma unroll
    for (int fc = 0; fc < 8; ++fc) {
      f16x8 a = wf[(kk * 8 + fc) * 64 + lane];
      acc[0][fc] = __builtin_amdgcn_mfma_f32_16x16x32_f16(a, xf[0][kk], acc[0][fc], 0, 0, 0);
      acc[1][fc] = __builtin_amdgcn_mfma_f32_16x16x32_f16(a, xf[1][kk], acc[1][fc], 0, 0, 0);
    }
  f16x8 hf[2][4];
#pragma unroll
  for (int fc = 0; fc < 8; ++fc) {
    float4 bv = *(const float4*)(bA + fc * 16 + rg * 4);
#pragma unroll
    for (int rs = 0; rs < 2; ++rs) {
      acc[rs][fc][0] = fmaxf(acc[rs][fc][0] + bv.x, 0.f);
      acc[rs][fc][1] = fmaxf(acc[rs][fc][1] + bv.y, 0.f);
      acc[rs][fc][2] = fmaxf(acc[rs][fc][2] + bv.z, 0.f);
      acc[rs][fc][3] = fmaxf(acc[rs][fc][3] + bv.w, 0.f);
    }
  }
#pragma unroll
  for (int rs = 0; rs < 2; ++rs)
#pragma unroll
    for (int kk = 0; kk < 4; ++kk)
      hf[rs][kk] = xpose(acc[rs][2 * kk], acc[rs][2 * kk + 1], rg);
  // ---- layer 2 (W22, 256 cols): two 128-col halves, wf restaged per half
  for (int h = 0; h < 2; ++h) {
    __syncthreads();                       // prior wf reads complete
#pragma unroll
    for (int i = 0; i < 8; ++i) {
      int id = t + i * 256;                // 0..2047
      int lj = id & 63, fcl = (id >> 6) & 7, kk = id >> 9;
      wf[id] = wfB[(kk * 16 + h * 8 + fcl) * 64 + lj];
    }
    __syncthreads();
#pragma unroll
    for (int rs = 0; rs < 2; ++rs)
#pragma unroll
      for (int fc = 0; fc < 8; ++fc) acc[rs][fc] = (f32x4){0.f, 0.f, 0.f, 0.f};
#pragma unroll
    for (int kk = 0; kk < 4; ++kk)
#pragma unroll
      for (int fc = 0; fc < 8; ++fc) {
        f16x8 b = wf[(kk * 8 + fc) * 64 + lane];
        acc[0][fc] = __builtin_amdgcn_mfma_f32_16x16x32_f16(hf[0][kk], b, acc[0][fc], 0, 0, 0);
        acc[1][fc] = __builtin_amdgcn_mfma_f32_16x16x32_f16(hf[1][kk], b, acc[1][fc], 0, 0, 0);
      }
    // epilogue: lane holds 4 consecutive rows x fixed col -> run-compress
#pragma unroll
    for (int fc = 0; fc < 8; ++fc) {
      int col = h * 128 + fc * 16 + l16;
      float bv = bB[col];
#pragma unroll
      for (int fr = 0; fr < 2; ++fr) {
        f32x4 a = acc[fr][fc];
        float run = fmaxf(a[0] + bv, 0.f);
#pragma unroll
        for (int j = 1; j < 4; ++j) {
          float v = fmaxf(a[j] + bv, 0.f);
          if (g4[fr][j] == g4[fr][j - 1]) run += v;
          else {
            int g = g4[fr][j - 1];
            if (g >= 0) {
              int d = g - g0;
              if (d >= 0 && d < 8) atomicAdd(&pool_l[d * 256 + col], run);
              else atomicAdd(&pool[g * 256 + col], run);
            }
            run = v;
          }
        }
        int g = g4[fr][3];
        if (g >= 0) {
          int d = g - g0;
          if (d >= 0 && d < 8) atomicAdd(&pool_l[d * 256 + col], run);
          else atomicAdd(&pool[g * 256 + col], run);
        }
      }
    }
  }
  __syncthreads();
#pragma unroll
  for (int j = 0; j < 8; ++j) {
    int idx = j * 256 + t;
    int g = g0 + (idx >> 8), col = idx & 255;
    float v = pool_l[idx];
    if (g < GRAPHS && v != 0.f) atomicAdd(&pool[g * 256 + col], v);
  }
}

// ---------------- LayerNorm finalize ----------------
__global__ void k_final(const float* __restrict__ pool, const int* __restrict__ starts,
                        const float* __restrict__ gamma, const float* __restrict__ beta,
                        float* __restrict__ out) {
  __shared__ float2 red[256];
  int g = blockIdx.x, ch = threadIdx.x;
  int cnt = starts[g + 1] - starts[g];
  float p = pool[g * 256 + ch] / fmaxf((float)cnt, 1.f);
  red[ch] = make_float2(p, p * p);
  __syncthreads();
  for (int off = 128; off > 0; off >>= 1) {
    if (ch < off) { red[ch].x += red[ch + off].x; red[ch].y += red[ch + off].y; }
    __syncthreads();
  }
  float mu = red[0].x * (1.f / 256.f);
  float var = red[0].y * (1.f / 256.f) - mu * mu;
  out[g * 256 + ch] = (p - mu) * rsqrtf(var + 1e-5f) * gamma[ch] + beta[ch];
}

extern "C" void kernel_launch(void* const* d_in, const int* in_sizes, int n_in,
                              void* d_out, int out_size, void* d_ws, size_t ws_size,
                              hipStream_t stream) {
  const float* x     = (const float*)d_in[0];
  const int*   ei    = (const int*)d_in[1];
  const int*   batch = (const int*)d_in[2];
  const float* W11 = (const float*)d_in[3];  const float* b11 = (const float*)d_in[4];
  const float* W12 = (const float*)d_in[5];  const float* b12 = (const float*)d_in[6];
  const float* W21 = (const float*)d_in[7];  const float* b21 = (const float*)d_in[8];
  const float* W22 = (const float*)d_in[9];  const float* b22 = (const float*)d_in[10];
  const float* gamma = (const float*)d_in[11];
  const float* beta  = (const float*)d_in[12];
  float* out = (float*)d_out;

  int n = in_sizes[0] / 128;   // 100000
  int e = in_sizes[1] / 2;     // 1600000
  const int* src = ei;
  const int* dstv = ei + e;

  int NB = (n + 511) >> 9;                 // 196 buckets
  int NW = (e + CHUNKC - 1) / CHUNKC;      // 400 workgroups
  int NS = NB * NW;                        // 78400 scan entries

  char* ws = (char*)d_ws;
  auto alloc = [&](size_t bytes) { char* p = ws; ws += (bytes + 15) & ~(size_t)15; return p; };
  _Float16* P0 = (_Float16*)alloc((size_t)(n + 1) * 128 * 2);  // +1: zero pad row
  _Float16* P1 = (_Float16*)alloc((size_t)(n + 1) * 128 * 2);
  float* pool  = (float*)alloc((size_t)GRAPHS * 256 * 4);
  int* ptr     = (int*)alloc((size_t)(n + 1) * 4);
  int* csr     = (int*)alloc((size_t)e * 4);
  int* part    = (int*)alloc((size_t)e * 4);
  int* histG   = (int*)alloc((size_t)NS * 4);
  int* off     = (int*)alloc((size_t)NS * 4);
  int* bsum    = (int*)alloc(256 * 4);
  int* starts  = (int*)alloc((GRAPHS + 1) * 4);
  f16x8* f11 = (f16x8*)alloc(2048 * 16);
  f16x8* f12 = (f16x8*)alloc(2048 * 16);
  f16x8* f21 = (f16x8*)alloc(2048 * 16);
  f16x8* f22 = (f16x8*)alloc(4096 * 16);

  int cvtb = (n * 32 + 255) / 256;         // 12500
  int wpb = 40;
  int poolb = (GRAPHS * 256 + 255) / 256;  // 128
  int prepb = cvtb + wpb + poolb + 1;

  int nbk = (NS + 1023) / 1024;            // 77 scan blocks
  k_prep <<<prepb, 256, 0, stream>>>(x, P0, P1, n, W11, W12, W21, W22,
                                     f11, f12, f21, f22, pool, cvtb, wpb, poolb);
  k_hist <<<NW, 256, 0, stream>>>(dstv, histG, e, NB, NW);
  k_scanA<<<nbk, 256, 0, stream>>>(histG, off, bsum, NS);
  k_scanB<<<1, 256, 0, stream>>>(bsum, nbk, batch, starts, n);
  k_scanC<<<(NS + 255) / 256, 256, 0, stream>>>(off, bsum, NS);
  k_part <<<NW, 256, 0, stream>>>(src, dstv, histG, off, part, e, NB, NW);
  k_csrb <<<NB, 256, 0, stream>>>(part, off, ptr, csr, e, NB, NW, n);

  int mb = (n + 127) / 128;                // 782 MLP tiles
  int ab = (n * 64 + 255) / 256;

  k_agg_h<<<ab, 256, 0, stream>>>(P0, P1, ptr, csr, n);               // P1 = x + agg(x)
  k_mlp128<<<mb, 256, 0, stream>>>(P1, f11, b11, f12, b12, P0, n);    // P0 = h1
  k_agg_h<<<ab, 256, 0, stream>>>(P0, P1, ptr, csr, n);               // P1 = h1 + agg(h1)
  k_mlp_pool<<<mb, 256, 0, stream>>>(P1, f21, b21, f22, b22, batch, pool, n);
  k_final<<<GRAPHS, 256, 0, stream>>>(pool, starts, gamma, beta, out);
}

// Round 12
// 276.914 us; speedup vs baseline: 1.3205x; 1.0188x over previous
//
#include <hip/hip_runtime.h>

#define GRAPHS 128
#define CHUNKC 4000

typedef _Float16 f16x8 __attribute__((ext_vector_type(8)));
typedef _Float16 f16x4 __attribute__((ext_vector_type(4)));
typedef _Float16 f16x2 __attribute__((ext_vector_type(2)));
typedef float f32x4 __attribute__((ext_vector_type(4)));

// v_fma_mix_f32: acc += (float)f16_half(w) in ONE VALU op (exact cvt+fma)
__device__ __forceinline__ void fmix_lo(float& a, int w) {
  asm("v_fma_mix_f32 %0, %1, 1.0, %0 op_sel:[0,0,0] op_sel_hi:[1,0,0]" : "+v"(a) : "v"(w));
}
__device__ __forceinline__ void fmix_hi(float& a, int w) {
  asm("v_fma_mix_f32 %0, %1, 1.0, %0 op_sel:[1,0,0] op_sel_hi:[1,0,0]" : "+v"(a) : "v"(w));
}

// -------- mega-prep: edge hist + x cvt + weight frag prep + pool zero + pad rows --------
__global__ void k_prep(const int* __restrict__ dst, int* __restrict__ histG,
                       int e, int NB, int NW,
                       const float* __restrict__ x, _Float16* __restrict__ P0,
                       _Float16* __restrict__ P1, int n,
                       const float* __restrict__ W11, const float* __restrict__ W12,
                       const float* __restrict__ W21, const float* __restrict__ W22,
                       f16x8* __restrict__ f11, f16x8* __restrict__ f12,
                       f16x8* __restrict__ f21, f16x8* __restrict__ f22,
                       float* __restrict__ pool, int cvtb, int wpb, int poolb) {
  __shared__ int h[256];
  int b = blockIdx.x, t = threadIdx.x;
  if (b < NW) {                            // edge histogram (bucket = dst>>9)
    h[t] = 0; __syncthreads();
    int lo = b * CHUNKC, hi = min(lo + CHUNKC, e);
    for (int i = lo + t; i < hi; i += 256) atomicAdd(&h[dst[i] >> 9], 1);
    __syncthreads();
    if (t < NB) histG[t * NW + b] = h[t];
    return;
  }
  b -= NW;
  if (b < cvtb) {                          // x conversion (f16x4 granules)
    int i = b * 256 + t;
    if (i < n * 32) {
      float4 v = ((const float4*)x)[i];
      f16x4 hh = { (_Float16)v.x, (_Float16)v.y, (_Float16)v.z, (_Float16)v.w };
      ((f16x4*)P0)[i] = hh;
    }
    return;
  }
  b -= cvtb;
  if (b < wpb) {                           // weight fragment prep
    int id = b * 256 + t;
    const float* W; f16x8* F; int C, cid, fshift;
    if (id < 2048)       { W = W11; F = f11; C = 128; cid = id;        fshift = 3; }
    else if (id < 4096)  { W = W12; F = f12; C = 128; cid = id - 2048; fshift = 3; }
    else if (id < 6144)  { W = W21; F = f21; C = 128; cid = id - 4096; fshift = 3; }
    else if (id < 10240) { W = W22; F = f22; C = 256; cid = id - 6144; fshift = 4; }
    else return;
    int lane = cid & 63;
    int rest = cid >> 6;
    int fc = rest & ((1 << fshift) - 1);
    int kk = rest >> fshift;
    int cout = fc * 16 + (lane & 15);
    int kb = kk * 32 + (lane >> 4) * 8;
    f16x8 v;
#pragma unroll
    for (int q = 0; q < 8; ++q) v[q] = (_Float16)W[(size_t)(kb + q) * C + cout];
    F[cid] = v;
    return;
  }
  b -= wpb;
  if (b < poolb) {                         // pool zero
    int i = b * 256 + t;
    if (i < GRAPHS * 256) pool[i] = 0.f;
    return;
  }
  if (t < 128) P0[(size_t)n * 128 + t] = (_Float16)0.f;      // pad rows
  else P1[(size_t)n * 128 + (t - 128)] = (_Float16)0.f;
}

// ---- 3-phase parallel exclusive scan (phase C folded into consumers) ----
__global__ void k_scanA(const int* __restrict__ in, int* __restrict__ out,
                        int* __restrict__ bsum, int N) {
  __shared__ int s[256];
  int t = threadIdx.x, b = blockIdx.x;
  int base = b * 1024 + t * 4;
  int v[4]; int tot = 0;
#pragma unroll
  for (int j = 0; j < 4; ++j) { int i = base + j; v[j] = (i < N) ? in[i] : 0; tot += v[j]; }
  s[t] = tot; __syncthreads();
  for (int o = 1; o < 256; o <<= 1) {
    int x = (t >= o) ? s[t - o] : 0;
    __syncthreads(); s[t] += x; __syncthreads();
  }
  int run = s[t] - tot;
#pragma unroll
  for (int j = 0; j < 4; ++j) { int i = base + j; if (i < N) out[i] = run; run += v[j]; }
  if (t == 255) bsum[b] = s[255];
}

__global__ void k_scanB(int* bsum, int nb, const int* __restrict__ batch,
                        int* __restrict__ starts, int n) {
  __shared__ int s[256];
  int t = threadIdx.x;
  int v = (t < nb) ? bsum[t] : 0;
  s[t] = v; __syncthreads();
  for (int o = 1; o < 256; o <<= 1) {
    int x = (t >= o) ? s[t - o] : 0;
    __syncthreads(); s[t] += x; __syncthreads();
  }
  if (t < nb) bsum[t] = s[t] - v;
  if (t <= GRAPHS) {
    int lo = 0, hi = n;
    while (lo < hi) { int mid = (lo + hi) >> 1; if (batch[mid] < t) lo = mid + 1; else hi = mid; }
    starts[t] = lo;
  }
}

__global__ void k_part(const int* __restrict__ src, const int* __restrict__ dst,
                       const int* __restrict__ histG, const int* __restrict__ off,
                       const int* __restrict__ bsum,
                       int* __restrict__ part, int e, int NB, int NW) {
  __shared__ int hist[256], lbA[256], lbB[256], stmp[256];
  __shared__ int els[CHUNKC];
  int t = threadIdx.x, w = blockIdx.x;
  int hv = (t < NB) ? histG[t * NW + w] : 0;
  hist[t] = hv; stmp[t] = hv; __syncthreads();
  for (int o = 1; o < 256; o <<= 1) {
    int x = (t >= o) ? stmp[t - o] : 0;
    __syncthreads(); stmp[t] += x; __syncthreads();
  }
  lbA[t] = stmp[t] - hv; lbB[t] = stmp[t] - hv;
  __syncthreads();
  int lo = w * CHUNKC, hi = min(lo + CHUNKC, e);
  for (int i = lo + t; i < hi; i += 256) {
    int d = dst[i];
    int p = atomicAdd(&lbB[d >> 9], 1);
    els[p] = src[i] | ((d & 511) << 17);   // src < 2^17, dstlow < 2^9
  }
  __syncthreads();
  int ln = t & 63, wv = t >> 6;
  for (int b = wv; b < NB; b += 4) {
    int c = hist[b], lb = lbA[b];
    int idx = b * NW + w;
    long g = off[idx] + bsum[idx >> 10];
    for (int j = ln; j < c; j += 64) part[g + j] = els[lb + j];
  }
}

__global__ void k_csrb(const int* __restrict__ part, const int* __restrict__ off,
                       const int* __restrict__ bsum,
                       int* __restrict__ ptr, int* __restrict__ csr,
                       int e, int NB, int NW, int n) {
  __shared__ int nh[512], ncur[512], stmp[256];
  int t = threadIdx.x, b = blockIdx.x;
  int i0 = b * NW;
  int s0 = off[i0] + bsum[i0 >> 10];
  int e0 = e;
  if (b + 1 < NB) { int i1 = (b + 1) * NW; e0 = off[i1] + bsum[i1 >> 10]; }
  nh[t] = 0; nh[t + 256] = 0; __syncthreads();
  for (int i = s0 + t; i < e0; i += 256) atomicAdd(&nh[((unsigned)part[i]) >> 17], 1);
  __syncthreads();
  int v0 = nh[2 * t], v1 = nh[2 * t + 1];
  int ps = v0 + v1;
  stmp[t] = ps; __syncthreads();
  for (int o = 1; o < 256; o <<= 1) {
    int x = (t >= o) ? stmp[t - o] : 0;
    __syncthreads(); stmp[t] += x; __syncthreads();
  }
  int base = stmp[t] - ps;
  __syncthreads();
  nh[2 * t] = base;   nh[2 * t + 1] = base + v0;
  ncur[2 * t] = base; ncur[2 * t + 1] = base + v0;
  __syncthreads();
#pragma unroll
  for (int q = 0; q < 2; ++q) {
    int vv = t + q * 256;
    int node = (b << 9) + vv;
    if (node <= n) ptr[node] = s0 + nh[vv];   // covers sentinel ptr[n]=e
  }
  for (int i = s0 + t; i < e0; i += 256) {
    int u = part[i];
    int p = atomicAdd(&ncur[((unsigned)u) >> 17], 1);
    csr[s0 + p] = u & 0x1FFFF;
  }
}

// ------------- aggregation: out[i] = in[i] + sum_N in[j], f16, f32 accum -------------
__global__ void k_agg_h(const _Float16* __restrict__ in, _Float16* __restrict__ out,
                        const int* __restrict__ ptr, const int* __restrict__ csr, int n) {
  int gid = blockIdx.x * 256 + threadIdx.x;
  int node = gid >> 6, lane = gid & 63;
  if (node >= n) return;
  const f16x8* inp = (const f16x8*)in;
  int cb = lane & 15, rg = lane >> 4;
  f16x8 self = inp[(size_t)node * 16 + cb];
  float acc[8];
#pragma unroll
  for (int c = 0; c < 8; ++c) acc[c] = (rg == 0) ? (float)self[c] : 0.f;
  int s = ptr[node], deg = ptr[node + 1] - s;
  union W { f16x8 v; int i[4]; };
  for (int seg = 0; seg < deg; seg += 64) {
    int my = (seg + lane < deg) ? csr[s + seg + lane] : n;
    int segn = min(deg - seg, 64);
    for (int b2 = 0; b2 < segn; b2 += 32) {
      int jj[8]; W w[8];
#pragma unroll
      for (int u = 0; u < 8; ++u) jj[u] = __shfl(my, b2 + u * 4 + rg);
#pragma unroll
      for (int u = 0; u < 8; ++u) w[u].v = inp[(size_t)jj[u] * 16 + cb];
#pragma unroll
      for (int u = 0; u < 8; ++u)
#pragma unroll
        for (int p = 0; p < 4; ++p) {
          fmix_lo(acc[2 * p], w[u].i[p]);
          fmix_hi(acc[2 * p + 1], w[u].i[p]);
        }
    }
  }
#pragma unroll
  for (int c = 0; c < 8; ++c) {
    acc[c] += __shfl_xor(acc[c], 16);
    acc[c] += __shfl_xor(acc[c], 32);
  }
  if (rg == 0) {
    f16x8 r;
#pragma unroll
    for (int c = 0; c < 8; ++c) r[c] = (_Float16)acc[c];
    ((f16x8*)out)[(size_t)node * 16 + cb] = r;
  }
}

// ---- in-register fragment transpose (4-lane-group shfl_xor) ----
__device__ __forceinline__ f16x8 xpose(f32x4 aE, f32x4 aO, int rg) {
  union U2 { _Float16 h[2]; int i; };
  union U8 { int i[4]; f16x8 v; };
  U2 e01, e23, o01, o23;
  e01.h[0] = (_Float16)aE[0]; e01.h[1] = (_Float16)aE[1];
  e23.h[0] = (_Float16)aE[2]; e23.h[1] = (_Float16)aE[3];
  o01.h[0] = (_Float16)aO[0]; o01.h[1] = (_Float16)aO[1];
  o23.h[0] = (_Float16)aO[2]; o23.h[1] = (_Float16)aO[3];
  int e01x1 = __shfl_xor(e01.i, 16), e01x2 = __shfl_xor(e01.i, 32), e01x3 = __shfl_xor(e01.i, 48);
  int e23x1 = __shfl_xor(e23.i, 16), e23x2 = __shfl_xor(e23.i, 32), e23x3 = __shfl_xor(e23.i, 48);
  int o01x1 = __shfl_xor(o01.i, 16), o01x2 = __shfl_xor(o01.i, 32), o01x3 = __shfl_xor(o01.i, 48);
  int o23x1 = __shfl_xor(o23.i, 16), o23x2 = __shfl_xor(o23.i, 32), o23x3 = __shfl_xor(o23.i, 48);
  U8 r;
  r.i[0] = rg == 0 ? e01.i : rg == 1 ? e01x3 : rg == 2 ? o01x2 : o01x1;
  r.i[1] = rg == 0 ? e23.i : rg == 1 ? e23x3 : rg == 2 ? o23x2 : o23x1;
  r.i[2] = rg == 0 ? e01x1 : rg == 1 ? e01x2 : rg == 2 ? o01x3 : o01.i;
  r.i[3] = rg == 0 ? e23x1 : rg == 1 ? e23x2 : rg == 2 ? o23x3 : o23.i;
  return r.v;
}

// ------- fused MLP: out = relu(relu(in@WA+bA)@WB+bB), 128->128->128 -------
__launch_bounds__(256, 3)
__global__ void k_mlp128(const _Float16* __restrict__ in, const f16x8* __restrict__ wfA,
                         const float* __restrict__ bA, const f16x8* __restrict__ wfB,
                         const float* __restrict__ bB, _Float16* __restrict__ out, int n) {
  __shared__ f16x8 wf[2048];   // 32 KB, holds WA frags then WB frags
  int t = threadIdx.x;
  int r0 = blockIdx.x * 128;
  int lane = t & 63, w = t >> 6;
  int l16 = lane & 15, rg = lane >> 4;
  int rw = w * 32;
  const f16x8* inp = (const f16x8*)in;
#pragma unroll
  for (int i = 0; i < 8; ++i) wf[t + i * 256] = wfA[t + i * 256];
  int ra0 = r0 + rw + l16;      if (ra0 > n) ra0 = n;   // row n = zero pad row
  int ra1 = r0 + rw + 16 + l16; if (ra1 > n) ra1 = n;
  f16x8 xf[2][4];
#pragma unroll
  for (int kk = 0; kk < 4; ++kk) {
    xf[0][kk] = inp[(size_t)ra0 * 16 + kk * 4 + rg];
    xf[1][kk] = inp[(size_t)ra1 * 16 + kk * 4 + rg];
  }
  __syncthreads();
  f32x4 acc[2][8];
#pragma unroll
  for (int rs = 0; rs < 2; ++rs)
#pragma unroll
    for (int fc = 0; fc < 8; ++fc) acc[rs][fc] = (f32x4){0.f, 0.f, 0.f, 0.f};
#pragma unroll
  for (int kk = 0; kk < 4; ++kk)
#pragma unroll
    for (int fc = 0; fc < 8; ++fc) {
      f16x8 a = wf[(kk * 8 + fc) * 64 + lane];
      acc[0][fc] = __builtin_amdgcn_mfma_f32_16x16x32_f16(a, xf[0][kk], acc[0][fc], 0, 0, 0);
      acc[1][fc] = __builtin_amdgcn_mfma_f32_16x16x32_f16(a, xf[1][kk], acc[1][fc], 0, 0, 0);
    }
  f16x8 hf[2][4];
#pragma unroll
  for (int fc = 0; fc < 8; ++fc) {
    float4 bv = *(const float4*)(bA + fc * 16 + rg * 4);
#pragma unroll
    for (int rs = 0; rs < 2; ++rs) {
      acc[rs][fc][0] = fmaxf(acc[rs][fc][0] + bv.x, 0.f);
      acc[rs][fc][1] = fmaxf(acc[rs][fc][1] + bv.y, 0.f);
      acc[rs][fc][2] = fmaxf(acc[rs][fc][2] + bv.z, 0.f);
      acc[rs][fc][3] = fmaxf(acc[rs][fc][3] + bv.w, 0.f);
    }
  }
#pragma unroll
  for (int rs = 0; rs < 2; ++rs)
#pragma unroll
    for (int kk = 0; kk < 4; ++kk)
      hf[rs][kk] = xpose(acc[rs][2 * kk], acc[rs][2 * kk + 1], rg);
  __syncthreads();                       // all waves done reading WA frags
#pragma unroll
  for (int i = 0; i < 8; ++i) wf[t + i * 256] = wfB[t + i * 256];
  __syncthreads();
#pragma unroll
  for (int rs = 0; rs < 2; ++rs)
#pragma unroll
    for (int fc = 0; fc < 8; ++fc) acc[rs][fc] = (f32x4){0.f, 0.f, 0.f, 0.f};
#pragma unroll
  for (int kk = 0; kk < 4; ++kk)
#pragma unroll
    for (int fc = 0; fc < 8; ++fc) {
      f16x8 b = wf[(kk * 8 + fc) * 64 + lane];
      acc[0][fc] = __builtin_amdgcn_mfma_f32_16x16x32_f16(b, hf[0][kk], acc[0][fc], 0, 0, 0);
      acc[1][fc] = __builtin_amdgcn_mfma_f32_16x16x32_f16(b, hf[1][kk], acc[1][fc], 0, 0, 0);
    }
#pragma unroll
  for (int fc = 0; fc < 8; ++fc) {
    float4 bv = *(const float4*)(bB + fc * 16 + rg * 4);
#pragma unroll
    for (int rs = 0; rs < 2; ++rs) {
      acc[rs][fc][0] = fmaxf(acc[rs][fc][0] + bv.x, 0.f);
      acc[rs][fc][1] = fmaxf(acc[rs][fc][1] + bv.y, 0.f);
      acc[rs][fc][2] = fmaxf(acc[rs][fc][2] + bv.z, 0.f);
      acc[rs][fc][3] = fmaxf(acc[rs][fc][3] + bv.w, 0.f);
    }
  }
  f16x8* outp = (f16x8*)out;
#pragma unroll
  for (int rs = 0; rs < 2; ++rs) {
    int row = r0 + rw + rs * 16 + l16;
#pragma unroll
    for (int kk = 0; kk < 4; ++kk) {
      f16x8 o = xpose(acc[rs][2 * kk], acc[rs][2 * kk + 1], rg);
      if (row < n) outp[(size_t)row * 16 + kk * 4 + rg] = o;
    }
  }
}

// ------- fused MLP + pool, COLUMN-SPLIT: blockIdx&1 selects W22 128-col half -------
// Layer A recomputed per half (cheap); each block has ONE wfB stage in its chain.
__launch_bounds__(256, 3)
__global__ void k_mlp_pool(const _Float16* __restrict__ in, const f16x8* __restrict__ wfA,
                           const float* __restrict__ bA, const f16x8* __restrict__ wfB,
                           const float* __restrict__ bB, const int* __restrict__ batch,
                           float* __restrict__ pool, int n) {
  __shared__ f16x8 wf[2048];     // 32 KB
  __shared__ float pool_l[8 * 128];
  int t = threadIdx.x;
  int h = blockIdx.x & 1;
  int r0 = (blockIdx.x >> 1) * 128;
  int lane = t & 63, w = t >> 6;
  int l16 = lane & 15, rg = lane >> 4;
  int rw = w * 32;
  const f16x8* inp = (const f16x8*)in;
#pragma unroll
  for (int j = 0; j < 4; ++j) pool_l[j * 256 + t] = 0.f;
#pragma unroll
  for (int i = 0; i < 8; ++i) wf[t + i * 256] = wfA[t + i * 256];
  int ra0 = r0 + rw + l16;      if (ra0 > n) ra0 = n;
  int ra1 = r0 + rw + 16 + l16; if (ra1 > n) ra1 = n;
  f16x8 xf[2][4];
#pragma unroll
  for (int kk = 0; kk < 4; ++kk) {
    xf[0][kk] = inp[(size_t)ra0 * 16 + kk * 4 + rg];
    xf[1][kk] = inp[(size_t)ra1 * 16 + kk * 4 + rg];
  }
  int g0 = batch[r0];
  int rloc = rw + rg * 4;
  int g4[2][4];
#pragma unroll
  for (int fr = 0; fr < 2; ++fr)
#pragma unroll
    for (int j = 0; j < 4; ++j) {
      int row = r0 + rloc + fr * 16 + j;
      g4[fr][j] = (row < n) ? batch[row] : -1;
    }
  __syncthreads();
  f32x4 acc[2][8];
#pragma unroll
  for (int rs = 0; rs < 2; ++rs)
#pragma unroll
    for (int fc = 0; fc < 8; ++fc) acc[rs][fc] = (f32x4){0.f, 0.f, 0.f, 0.f};
#pragma unroll
  for (int kk = 0; kk < 4; ++kk)
#pragma unroll
    for (int fc = 0; fc < 8; ++fc) {
      f16x8 a = wf[(kk * 8 + fc) * 64 + lane];
      acc[0][fc] = __builtin_amdgcn_mfma_f32_16x16x32_f16(a, xf[0][kk], acc[0][fc], 0, 0, 0);
      acc[1][fc] = __builtin_amdgcn_mfma_f32_16x16x32_f16(a, xf[1][kk], acc[1][fc], 0, 0, 0);
    }
  f16x8 hf[2][4];
#pragma unroll
  for (int fc = 0; fc < 8; ++fc) {
    float4 bv = *(const float4*)(bA + fc * 16 + rg * 4);
#pragma unroll
    for (int rs = 0; rs < 2; ++rs) {
      acc[rs][fc][0] = fmaxf(acc[rs][fc][0] + bv.x, 0.f);
      acc[rs][fc][1] = fmaxf(acc[rs][fc][1] + bv.y, 0.f);
      acc[rs][fc][2] = fmaxf(acc[rs][fc][2] + bv.z, 0.f);
      acc[rs][fc][3] = fmaxf(acc[rs][fc][3] + bv.w, 0.f);
    }
  }
#pragma unroll
  for (int rs = 0; rs < 2; ++rs)
#pragma unroll
    for (int kk = 0; kk < 4; ++kk)
      hf[rs][kk] = xpose(acc[rs][2 * kk], acc[rs][2 * kk + 1], rg);
  // ---- layer 2: this block's 128-col half of W22
  __syncthreads();                       // prior wf reads complete
#pragma unroll
  for (int i = 0; i < 8; ++i) {
    int id = t + i * 256;                // 0..2047
    int lj = id & 63, fcl = (id >> 6) & 7, kk = id >> 9;
    wf[id] = wfB[(kk * 16 + h * 8 + fcl) * 64 + lj];
  }
  __syncthreads();
#pragma unroll
  for (int rs = 0; rs < 2; ++rs)
#pragma unroll
    for (int fc = 0; fc < 8; ++fc) acc[rs][fc] = (f32x4){0.f, 0.f, 0.f, 0.f};
#pragma unroll
  for (int kk = 0; kk < 4; ++kk)
#pragma unroll
    for (int fc = 0; fc < 8; ++fc) {
      f16x8 b = wf[(kk * 8 + fc) * 64 + lane];
      acc[0][fc] = __builtin_amdgcn_mfma_f32_16x16x32_f16(hf[0][kk], b, acc[0][fc], 0, 0, 0);
      acc[1][fc] = __builtin_amdgcn_mfma_f32_16x16x32_f16(hf[1][kk], b, acc[1][fc], 0, 0, 0);
    }
  // epilogue: lane holds 4 consecutive rows x fixed col -> run-compress
#pragma unroll
  for (int fc = 0; fc < 8; ++fc) {
    int col128 = fc * 16 + l16;
    float bv = bB[h * 128 + col128];
#pragma unroll
    for (int fr = 0; fr < 2; ++fr) {
      f32x4 a = acc[fr][fc];
      float run = fmaxf(a[0] + bv, 0.f);
#pragma unroll
      for (int j = 1; j < 4; ++j) {
        float v = fmaxf(a[j] + bv, 0.f);
        if (g4[fr][j] == g4[fr][j - 1]) run += v;
        else {
          int g = g4[fr][j - 1];
          if (g >= 0) {
            int d = g - g0;
            if (d >= 0 && d < 8) atomicAdd(&pool_l[d * 128 + col128], run);
            else atomicAdd(&pool[g * 256 + h * 128 + col128], run);
          }
          run = v;
        }
      }
      int g = g4[fr][3];
      if (g >= 0) {
        int d = g - g0;
        if (d >= 0 && d < 8) atomicAdd(&pool_l[d * 128 + col128], run);
        else atomicAdd(&pool[g * 256 + h * 128 + col128], run);
      }
    }
  }
  __syncthreads();
#pragma unroll
  for (int j = 0; j < 4; ++j) {
    int idx = j * 256 + t;
    int g = g0 + (idx >> 7), col128 = idx & 127;
    float v = pool_l[idx];
    if (g < GRAPHS && v != 0.f) atomicAdd(&pool[g * 256 + h * 128 + col128], v);
  }
}

// ---------------- LayerNorm finalize ----------------
__global__ void k_final(const float* __restrict__ pool, const int* __restrict__ starts,
                        const float* __restrict__ gamma, const float* __restrict__ beta,
                        float* __restrict__ out) {
  __shared__ float2 red[256];
  int g = blockIdx.x, ch = threadIdx.x;
  int cnt = starts[g + 1] - starts[g];
  float p = pool[g * 256 + ch] / fmaxf((float)cnt, 1.f);
  red[ch] = make_float2(p, p * p);
  __syncthreads();
  for (int off = 128; off > 0; off >>= 1) {
    if (ch < off) { red[ch].x += red[ch + off].x; red[ch].y += red[ch + off].y; }
    __syncthreads();
  }
  float mu = red[0].x * (1.f / 256.f);
  float var = red[0].y * (1.f / 256.f) - mu * mu;
  out[g * 256 + ch] = (p - mu) * rsqrtf(var + 1e-5f) * gamma[ch] + beta[ch];
}

extern "C" void kernel_launch(void* const* d_in, const int* in_sizes, int n_in,
                              void* d_out, int out_size, void* d_ws, size_t ws_size,
                              hipStream_t stream) {
  const float* x     = (const float*)d_in[0];
  const int*   ei    = (const int*)d_in[1];
  const int*   batch = (const int*)d_in[2];
  const float* W11 = (const float*)d_in[3];  const float* b11 = (const float*)d_in[4];
  const float* W12 = (const float*)d_in[5];  const float* b12 = (const float*)d_in[6];
  const float* W21 = (const float*)d_in[7];  const float* b21 = (const float*)d_in[8];
  const float* W22 = (const float*)d_in[9];  const float* b22 = (const float*)d_in[10];
  const float* gamma = (const float*)d_in[11];
  const float* beta  = (const float*)d_in[12];
  float* out = (float*)d_out;

  int n = in_sizes[0] / 128;   // 100000
  int e = in_sizes[1] / 2;     // 1600000
  const int* src = ei;
  const int* dstv = ei + e;

  int NB = (n + 511) >> 9;                 // 196 buckets
  int NW = (e + CHUNKC - 1) / CHUNKC;      // 400 workgroups
  int NS = NB * NW;                        // 78400 scan entries

  char* ws = (char*)d_ws;
  auto alloc = [&](size_t bytes) { char* p = ws; ws += (bytes + 15) & ~(size_t)15; return p; };
  _Float16* P0 = (_Float16*)alloc((size_t)(n + 1) * 128 * 2);  // +1: zero pad row
  _Float16* P1 = (_Float16*)alloc((size_t)(n + 1) * 128 * 2);
  float* pool  = (float*)alloc((size_t)GRAPHS * 256 * 4);
  int* ptr     = (int*)alloc((size_t)(n + 1) * 4);
  int* csr     = (int*)alloc((size_t)e * 4);
  int* part    = (int*)alloc((size_t)e * 4);
  int* histG   = (int*)alloc((size_t)NS * 4);
  int* off     = (int*)alloc((size_t)NS * 4);
  int* bsum    = (int*)alloc(256 * 4);
  int* starts  = (int*)alloc((GRAPHS + 1) * 4);
  f16x8* f11 = (f16x8*)alloc(2048 * 16);
  f16x8* f12 = (f16x8*)alloc(2048 * 16);
  f16x8* f21 = (f16x8*)alloc(2048 * 16);
  f16x8* f22 = (f16x8*)alloc(4096 * 16);

  int cvtb = (n * 32 + 255) / 256;         // 12500
  int wpb = 40;
  int poolb = (GRAPHS * 256 + 255) / 256;  // 128
  int prepb = NW + cvtb + wpb + poolb + 1;

  int nbk = (NS + 1023) / 1024;            // 77 scan blocks
  k_prep <<<prepb, 256, 0, stream>>>(dstv, histG, e, NB, NW, x, P0, P1, n,
                                     W11, W12, W21, W22, f11, f12, f21, f22,
                                     pool, cvtb, wpb, poolb);
  k_scanA<<<nbk, 256, 0, stream>>>(histG, off, bsum, NS);
  k_scanB<<<1, 256, 0, stream>>>(bsum, nbk, batch, starts, n);
  k_part <<<NW, 256, 0, stream>>>(src, dstv, histG, off, bsum, part, e, NB, NW);
  k_csrb <<<NB, 256, 0, stream>>>(part, off, bsum, ptr, csr, e, NB, NW, n);

  int mb = (n + 127) / 128;                // 782 MLP tiles
  int ab = (n * 64 + 255) / 256;

  k_agg_h<<<ab, 256, 0, stream>>>(P0, P1, ptr, csr, n);               // P1 = x + agg(x)
  k_mlp128<<<mb, 256, 0, stream>>>(P1, f11, b11, f12, b12, P0, n);    // P0 = h1
  k_agg_h<<<ab, 256, 0, stream>>>(P0, P1, ptr, csr, n);               // P1 = h1 + agg(h1)
  k_mlp_pool<<<mb * 2, 256, 0, stream>>>(P1, f21, b21, f22, b22, batch, pool, n);
  k_final<<<GRAPHS, 256, 0, stream>>>(pool, starts, gamma, beta, out);
}